// Round 12
// baseline (153.338 us; speedup 1.0000x reference)
//
#include <hip/hip_runtime.h>
#include <hip/hip_bf16.h>

// B=4, T=2048, C=1024, H=16, D=64. fp32 in/out.
// cast_x / transpose weights -> qkv_gemm (256x256 8-phase template, BK=64, 128KB LDS) ->
// tv -> attn (unchanged) -> out_gemm (gemm_core3, unchanged).

#define B_ 4
#define T_ 2048
#define C_ 1024
#define H_ 16
#define D_ 64
#define M_ (B_*T_)      // 8192

typedef unsigned short u16;
typedef unsigned short ushort8 __attribute__((ext_vector_type(8)));
typedef unsigned int uint4v __attribute__((ext_vector_type(4)));
typedef int int2v __attribute__((ext_vector_type(2)));
typedef __attribute__((ext_vector_type(8))) short bf16x8;
typedef __attribute__((ext_vector_type(4))) float f32x4;
typedef __attribute__((ext_vector_type(16))) float f32x16;

__device__ __forceinline__ u16 f2bf(float f) {
    __hip_bfloat16 h = __float2bfloat16(f);
    return *reinterpret_cast<u16*>(&h);
}
__device__ __forceinline__ unsigned pkt(float lo, float hi2) {
    return __builtin_amdgcn_perm(__float_as_uint(hi2), __float_as_uint(lo), 0x07060302u);
}
__device__ __forceinline__ void gload_lds16(const void* g, void* lds) {
    __builtin_amdgcn_global_load_lds((const __attribute__((address_space(1))) unsigned int*)g,
                                     (__attribute__((address_space(3))) unsigned int*)lds, 16, 0, 0);
}
__device__ __forceinline__ int swz4(int r) { return (r ^ (r >> 2)) & 3; }   // 64B-row granule swizzle

// ---------------- cast x -> bf16 ----------------
__global__ __launch_bounds__(256) void cast_x(const float* __restrict__ in, u16* __restrict__ out) {
    int i = (blockIdx.x * 256 + threadIdx.x) * 8;
    float4 a = *reinterpret_cast<const float4*>(in + i);
    float4 b = *reinterpret_cast<const float4*>(in + i + 4);
    ushort8 o;
    o[0]=f2bf(a.x); o[1]=f2bf(a.y); o[2]=f2bf(a.z); o[3]=f2bf(a.w);
    o[4]=f2bf(b.x); o[5]=f2bf(b.y); o[6]=f2bf(b.z); o[7]=f2bf(b.w);
    *reinterpret_cast<ushort8*>(out + i) = o;
}

// ---------------- 64x64 transpose+cast ----------------
__device__ __forceinline__ void ttile64(const float* __restrict__ in, int ldin,
                                        u16* __restrict__ out, int ldout, float scale) {
    __shared__ float t[64][65];
    const int tid = threadIdx.x;
    {
        int c = tid & 63, rr = tid >> 6;
        #pragma unroll
        for (int i = 0; i < 16; ++i) {
            int r = i * 4 + rr;
            t[r][c] = in[(size_t)r * ldin + c];
        }
    }
    __syncthreads();
    {
        int r2 = tid & 63, cg = tid >> 6;
        #pragma unroll
        for (int i = 0; i < 16; ++i) {
            int cc = i * 4 + cg;
            out[(size_t)cc * ldout + r2] = f2bf(t[r2][cc] * scale);
        }
    }
}

__global__ __launch_bounds__(256) void tw_qkv(const float* __restrict__ Wq, const float* __restrict__ Wk,
                                              const float* __restrict__ Wv, u16* __restrict__ Wt) {
    const int z = blockIdx.y;
    const int which = z >> 4, h = z & 15;
    const float* W = (which == 0 ? Wq : which == 1 ? Wk : Wv) + (size_t)h * C_ * D_;
    const int r0 = blockIdx.x * 64;
    const float scale = (which == 0) ? 0.03125f * 1.4426950408889634f : 1.f;  // C^-0.5 * log2(e)
    ttile64(W + (size_t)r0 * D_, D_, Wt + (size_t)(which * 16 + h) * 64 * C_ + r0, C_, scale);
}

__global__ __launch_bounds__(256) void tw_p(const float* __restrict__ Wp, u16* __restrict__ Wpt) {
    const int r0 = blockIdx.x * 64, c0 = blockIdx.y * 64;
    ttile64(Wp + (size_t)r0 * C_ + c0, C_, Wpt + (size_t)c0 * C_ + r0, C_, 1.f);
}

// ---------------- V [b,h,t,d] -> V^T [b,h,d,t] ----------------
__global__ __launch_bounds__(256) void tv(const u16* __restrict__ v, u16* __restrict__ vT) {
    __shared__ u16 t[64][72];
    const int tid = threadIdx.x;
    const int t0 = blockIdx.x * 64, bh = blockIdx.y;
    const u16* src = v + ((size_t)bh * T_ + t0) * D_;
    #pragma unroll
    for (int it = 0; it < 2; ++it) {
        int idx = it * 256 + tid;
        int r = idx >> 3, c8 = (idx & 7) * 8;
        *reinterpret_cast<ushort8*>(&t[r][c8]) =
            *reinterpret_cast<const ushort8*>(src + (size_t)r * D_ + c8);
    }
    __syncthreads();
    #pragma unroll
    for (int it = 0; it < 2; ++it) {
        int idx = it * 256 + tid;
        int d = idx >> 3, c8 = (idx & 7) * 8;
        ushort8 w;
        #pragma unroll
        for (int i = 0; i < 8; ++i) w[i] = t[c8 + i][d];
        *reinterpret_cast<ushort8*>(vT + ((size_t)bh * D_ + d) * T_ + t0 + c8) = w;
    }
}

// ================= QKV GEMM: 256x256 8-phase template =================
// BM=BN=256, BK=64, 512 thr = 8 waves (2M x 4N), wave tile 128x64, 16x16x32 MFMA.
// LDS 128KB: A [2dbuf][2half][128][64] bf16 at 0, B same at byte 65536.
// Per tile: vmcnt(0) -> s_barrier -> issue 8 gloads(t+1, other dbuf) ->
//           4 quadrants { ds_read frags, 16 MFMA } separated by sched_barrier.
// Granule swizzle g^=(row&7): inverse-swizzled global source, linear gload dest.
__global__ __launch_bounds__(512, 2) void qkv_gemm(const u16* __restrict__ A, const u16* __restrict__ Bt,
                                                   u16* __restrict__ q, u16* __restrict__ k,
                                                   u16* __restrict__ v) {
    __shared__ u16 lds[65536];   // 128 KiB
    const int tid = threadIdx.x;
    const int wid = tid >> 6, lane = tid & 63;
    const int l16 = lane & 15, lq = lane >> 4;
    const int wr = wid >> 2, wc = wid & 3;
    const int m0 = blockIdx.x * 256, n0 = blockIdx.y * 256;

    f32x4 acc[8][4];
    #pragma unroll
    for (int i = 0; i < 8; ++i)
        #pragma unroll
        for (int j = 0; j < 4; ++j) { acc[i][j][0]=0.f; acc[i][j][1]=0.f; acc[i][j][2]=0.f; acc[i][j][3]=0.f; }

    // staging: unit u<4 = A[half u>>1][it u&1], u>=4 = B[half][it]; 1 gload/thread/unit
    const u16* gsrc[8];
    int dstoff[8];
    #pragma unroll
    for (int u = 0; u < 8; ++u) {
        int it = u & 1, h = (u >> 1) & 1;
        int s = it * 512 + tid;
        int row = s >> 3, g = s & 7;
        int gs = (g ^ (row & 7)) * 8;
        if (u < 4) gsrc[u] = A  + (size_t)(m0 + h * 128 + row) * C_ + gs;
        else       gsrc[u] = Bt + (size_t)(n0 + h * 128 + row) * C_ + gs;
        dstoff[u] = (u < 4 ? 0 : 32768) + h * 8192 + s * 8;   // u16 units
    }

    // fragment base pointers (dbuf0; +32768 bytes for dbuf1)
    const char* lb = reinterpret_cast<const char*>(lds);
    const int gA0 = (lq ^ (l16 & 7)) * 16;          // kk=0 granule
    const int gA1 = ((4 + lq) ^ (l16 & 7)) * 16;    // kk=1
    const char* pA0 = lb + wr * 16384 + l16 * 128 + gA0;
    const char* pA1 = lb + wr * 16384 + l16 * 128 + gA1;
    const char* pB0 = lb + 65536 + (wc >> 1) * 16384 + ((wc & 1) * 64 + l16) * 128 + gA0;
    const char* pB1 = lb + 65536 + (wc >> 1) * 16384 + ((wc & 1) * 64 + l16) * 128 + gA1;

#define STAGE8(DSTD)                                                                 \
    {                                                                                \
        _Pragma("unroll")                                                            \
        for (int u = 0; u < 8; ++u) {                                                \
            gload_lds16(gsrc[u], lds + (DSTD) + dstoff[u]);                          \
            gsrc[u] += 64;                                                           \
        }                                                                            \
    }

#define QUAD(D, MB, NB)                                                              \
    {                                                                                \
        __builtin_amdgcn_s_setprio(1);                                               \
        _Pragma("unroll")                                                            \
        for (int kk = 0; kk < 2; ++kk)                                               \
            _Pragma("unroll")                                                        \
            for (int mt = 0; mt < 4; ++mt)                                           \
                _Pragma("unroll")                                                    \
                for (int nt = 0; nt < 2; ++nt)                                       \
                    acc[(MB) + mt][(NB) + nt] = __builtin_amdgcn_mfma_f32_16x16x32_bf16( \
                        Af[mt][kk], Bf[nt][kk], acc[(MB) + mt][(NB) + nt], 0, 0, 0); \
        __builtin_amdgcn_s_setprio(0);                                               \
        __builtin_amdgcn_sched_barrier(0);                                           \
    }

#define LDA(D, MB)                                                                   \
    _Pragma("unroll")                                                                \
    for (int mt = 0; mt < 4; ++mt) {                                                 \
        Af[mt][0] = *reinterpret_cast<const bf16x8*>(pA0 + (D) * 32768 + ((MB) + mt) * 2048); \
        Af[mt][1] = *reinterpret_cast<const bf16x8*>(pA1 + (D) * 32768 + ((MB) + mt) * 2048); \
    }

#define LDB(D, NB)                                                                   \
    _Pragma("unroll")                                                                \
    for (int nt = 0; nt < 2; ++nt) {                                                 \
        Bf[nt][0] = *reinterpret_cast<const bf16x8*>(pB0 + (D) * 32768 + ((NB) + nt) * 2048); \
        Bf[nt][1] = *reinterpret_cast<const bf16x8*>(pB1 + (D) * 32768 + ((NB) + nt) * 2048); \
    }

#define QTILE(D, SEN)                                                                \
    {                                                                                \
        asm volatile("s_waitcnt vmcnt(0)" ::: "memory");                             \
        __builtin_amdgcn_sched_barrier(0);                                           \
        __builtin_amdgcn_s_barrier();                                                \
        __builtin_amdgcn_sched_barrier(0);                                           \
        if (SEN) STAGE8(((D) ^ 1) * 16384);                                          \
        bf16x8 Af[4][2], Bf[2][2];                                                   \
        LDA(D, 0); LDB(D, 0); QUAD(D, 0, 0);      /* q0: rows 0-63,  cols 0-31 */    \
        LDB(D, 2); QUAD(D, 0, 2);                 /* q1: rows 0-63,  cols 32-63 */   \
        LDA(D, 4); QUAD(D, 4, 2);                 /* q2: rows 64-127,cols 32-63 */   \
        LDB(D, 0); QUAD(D, 4, 0);                 /* q3: rows 64-127,cols 0-31 */    \
    }

    STAGE8(0);                          // tile 0 -> dbuf 0
    for (int tt = 0; tt < 8; ++tt) {
        QTILE(0, true);                 // compute tile 2tt   (dbuf0), stage 2tt+1 -> dbuf1
        QTILE(1, tt != 7);              // compute tile 2tt+1 (dbuf1), stage 2tt+2 -> dbuf0
    }
#undef QTILE
#undef LDA
#undef LDB
#undef QUAD
#undef STAGE8

    // epilogue: scatter to q/k/v [B,H,T,D] bf16
    #pragma unroll
    for (int mt = 0; mt < 8; ++mt) {
        #pragma unroll
        for (int j = 0; j < 4; ++j) {
            int m = m0 + wr * 128 + mt * 16 + lq * 4 + j;
            int b = m >> 11, t = m & (T_ - 1);
            #pragma unroll
            for (int nt = 0; nt < 4; ++nt) {
                int n = n0 + wc * 64 + nt * 16 + l16;
                int which = n >> 10, h = (n >> 6) & 15, d = n & 63;
                u16* dst = (which == 0 ? q : which == 1 ? k : v);
                dst[((size_t)(b * H_ + h) * T_ + t) * D_ + d] = f2bf(acc[mt][nt][j]);
            }
        }
    }
}

// ---------------- GEMM core v3 (out_gemm): BM=256 BN=128 BK=32, 4 waves, wave 128x64 ----------------
__device__ __forceinline__ void gemm_core3(const u16* __restrict__ A, const u16* __restrict__ Bt,
                                           int m0, int n0, u16* lds, f32x16 (&acc)[4][2]) {
    const int tid = threadIdx.x;            // 256
    const int wid = tid >> 6, lane = tid & 63;
    const int l31 = lane & 31, hi = lane >> 5;
    const int wr = wid >> 1, wc = wid & 1;

    const u16* src[6];
    #pragma unroll
    for (int it = 0; it < 6; ++it) {
        int slot = it * 256 + tid;
        int row, g;
        const u16* base;
        if (it < 4) { row = slot >> 2; g = slot & 3; base = A + (size_t)(m0 + row) * C_; }
        else        { int s2 = slot - 1024; row = s2 >> 2; g = s2 & 3; base = Bt + (size_t)(n0 + row) * C_; }
        src[it] = base + ((g ^ swz4(row)) * 8);
    }

    const char* lb = reinterpret_cast<const char*>(lds);
    int aoff[2][4], boff[2][2];
    #pragma unroll
    for (int kk = 0; kk < 2; ++kk) {
        #pragma unroll
        for (int mt = 0; mt < 4; ++mt) {
            int row = wr * 128 + mt * 32 + l31;
            aoff[kk][mt] = row * 64 + (((kk * 2 + hi) ^ swz4(row)) & 3) * 16;
        }
        #pragma unroll
        for (int nt = 0; nt < 2; ++nt) {
            int row = wc * 64 + nt * 32 + l31;
            boff[kk][nt] = 16384 + row * 64 + (((kk * 2 + hi) ^ swz4(row)) & 3) * 16;
        }
    }

#define STG(BU16)                                                                   \
    {                                                                               \
        _Pragma("unroll")                                                           \
        for (int it = 0; it < 6; ++it) {                                            \
            gload_lds16(src[it], lds + (BU16) + (it * 256 + tid) * 8);              \
            src[it] += 32;                                                          \
        }                                                                           \
    }

    STG(0);
    STG(12288);

    #pragma unroll
    for (int t = 0; t < 32; ++t) {
        if (t < 31) { asm volatile("s_waitcnt vmcnt(6)" ::: "memory"); }
        else        { asm volatile("s_waitcnt vmcnt(0)" ::: "memory"); }
        __builtin_amdgcn_sched_barrier(0);
        __builtin_amdgcn_s_barrier();
        __builtin_amdgcn_sched_barrier(0);

        const char* lbuf = lb + (t & 1) * 24576;
        __builtin_amdgcn_s_setprio(1);
        #pragma unroll
        for (int kk = 0; kk < 2; ++kk) {
            bf16x8 bf0 = *reinterpret_cast<const bf16x8*>(lbuf + boff[kk][0]);
            bf16x8 bf1 = *reinterpret_cast<const bf16x8*>(lbuf + boff[kk][1]);
            #pragma unroll
            for (int mt = 0; mt < 4; ++mt) {
                bf16x8 af = *reinterpret_cast<const bf16x8*>(lbuf + aoff[kk][mt]);
                acc[mt][0] = __builtin_amdgcn_mfma_f32_32x32x16_bf16(af, bf0, acc[mt][0], 0, 0, 0);
                acc[mt][1] = __builtin_amdgcn_mfma_f32_32x32x16_bf16(af, bf1, acc[mt][1], 0, 0, 0);
            }
        }
        __builtin_amdgcn_s_setprio(0);
        __builtin_amdgcn_sched_barrier(0);
        __builtin_amdgcn_s_barrier();
        __builtin_amdgcn_sched_barrier(0);
        if (t + 2 < 32) STG((t & 1) * 12288);
    }
#undef STG
}

// ---------------- Output GEMM ----------------
__global__ __launch_bounds__(256, 2) void out_gemm(const u16* __restrict__ ob, const u16* __restrict__ Wpt,
                                                   const float* __restrict__ bp, float* __restrict__ out) {
    __shared__ u16 lds[2 * 12288];
    f32x16 acc[4][2];
    #pragma unroll
    for (int i = 0; i < 4; ++i)
        #pragma unroll
        for (int j = 0; j < 2; ++j)
            #pragma unroll
            for (int r = 0; r < 16; ++r) acc[i][j][r] = 0.f;
    const int m0 = blockIdx.x * 256, n0 = blockIdx.y * 128;
    gemm_core3(ob, Wpt, m0, n0, lds, acc);

    const int tid = threadIdx.x, wid = tid >> 6, lane = tid & 63;
    const int l31 = lane & 31, hi = lane >> 5;
    const int wr = wid >> 1, wc = wid & 1;
    #pragma unroll
    for (int mt = 0; mt < 4; ++mt) {
        #pragma unroll
        for (int nt = 0; nt < 2; ++nt) {
            int n = n0 + wc * 64 + nt * 32 + l31;
            float bv = bp[n];
            #pragma unroll
            for (int r = 0; r < 16; ++r) {
                int m = m0 + wr * 128 + mt * 32 + (r & 3) + 8 * (r >> 2) + 4 * hi;
                out[(size_t)m * C_ + n] = acc[mt][nt][r] + bv;
            }
        }
    }
}

// ---------------- attn compute tile (unchanged) ----------------
template<int CUR>
__device__ __forceinline__ void attn_tile(const char* const (&pf)[4], const bf16x8 (&qf)[4],
                                          const f32x16& z16, float& lrun,
                                          f32x16& oacc0, f32x16& oacc1,
                                          bool isdiag, int relq, int hi) {
    f32x16 st0, st1;
    __builtin_amdgcn_s_setprio(1);
    {
        bf16x8 ka0 = *reinterpret_cast<const bf16x8*>(pf[0] + CUR * 32768);
        bf16x8 ka1 = *reinterpret_cast<const bf16x8*>(pf[0] + CUR * 32768 + 4096);
        st0 = __builtin_amdgcn_mfma_f32_32x32x16_bf16(ka0, qf[0], z16, 0, 0, 0);
        st1 = __builtin_amdgcn_mfma_f32_32x32x16_bf16(ka1, qf[0], z16, 0, 0, 0);
    }
    #pragma unroll
    for (int kc = 1; kc < 4; ++kc) {
        bf16x8 ka0 = *reinterpret_cast<const bf16x8*>(pf[kc] + CUR * 32768);
        bf16x8 ka1 = *reinterpret_cast<const bf16x8*>(pf[kc] + CUR * 32768 + 4096);
        st0 = __builtin_amdgcn_mfma_f32_32x32x16_bf16(ka0, qf[kc], st0, 0, 0, 0);
        st1 = __builtin_amdgcn_mfma_f32_32x32x16_bf16(ka1, qf[kc], st1, 0, 0, 0);
    }
    __builtin_amdgcn_s_setprio(0);

    if (isdiag) {
        #pragma unroll
        for (int rr = 0; rr < 16; ++rr) {
            int sl = (rr & 3) + 8 * (rr >> 2) + 4 * hi;
            if (sl > relq)      st0[rr] = -INFINITY;
            if (sl + 32 > relq) st1[rr] = -INFINITY;
        }
    }

    float rsum = 0.f;
    #pragma unroll
    for (int rr = 0; rr < 16; ++rr) {
        st0[rr] = __builtin_amdgcn_exp2f(st0[rr]);
        st1[rr] = __builtin_amdgcn_exp2f(st1[rr]);
        rsum += st0[rr] + st1[rr];
    }
    rsum += __shfl_xor(rsum, 32);
    lrun += rsum;

    bf16x8 pa0, pa1, pa2, pa3;
#if __has_builtin(__builtin_amdgcn_permlane32_swap)
#define MK_PA(PA, SV, RB)                                                          \
    {                                                                              \
        int X0 = (int)pkt(SV[RB + 0], SV[RB + 1]);                                 \
        int X1 = (int)pkt(SV[RB + 2], SV[RB + 3]);                                 \
        int Y0 = (int)pkt(SV[RB + 4], SV[RB + 5]);                                 \
        int Y1 = (int)pkt(SV[RB + 6], SV[RB + 7]);                                 \
        int2v r0 = __builtin_amdgcn_permlane32_swap(X0, Y0, false, false);         \
        int2v r1 = __builtin_amdgcn_permlane32_swap(X1, Y1, false, false);         \
        uint4v w; w[0] = (unsigned)r0[0]; w[1] = (unsigned)r1[0];                  \
        w[2] = (unsigned)r0[1]; w[3] = (unsigned)r1[1];                            \
        PA = __builtin_bit_cast(bf16x8, w);                                        \
    }
#else
#define MK_PA(PA, SV, RB)                                                          \
    {                                                                              \
        unsigned X0 = pkt(SV[RB + 0], SV[RB + 1]);                                 \
        unsigned X1 = pkt(SV[RB + 2], SV[RB + 3]);                                 \
        unsigned Y0 = pkt(SV[RB + 4], SV[RB + 5]);                                 \
        unsigned sX0 = __shfl_xor(X0, 32), sY0 = __shfl_xor(Y0, 32);               \
        unsigned Y1 = pkt(SV[RB + 6], SV[RB + 7]);                                 \
        unsigned sX1 = __shfl_xor(X1, 32), sY1 = __shfl_xor(Y1, 32);               \
        uint4v w;                                                                  \
        w[0] = hi ? sY0 : X0; w[1] = hi ? sY1 : X1;                                \
        w[2] = hi ? Y0 : sX0; w[3] = hi ? Y1 : sX1;                                \
        PA = __builtin_bit_cast(bf16x8, w);                                        \
    }
#endif
    MK_PA(pa0, st0, 0); MK_PA(pa1, st0, 8); MK_PA(pa2, st1, 0); MK_PA(pa3, st1, 8);
#undef MK_PA

    __builtin_amdgcn_s_setprio(1);
#define PV_STEP(SCJ, PAV)                                                          \
    {                                                                              \
        bf16x8 va0 = *reinterpret_cast<const bf16x8*>(pf[SCJ] + CUR * 32768 + 16384);        \
        bf16x8 va1 = *reinterpret_cast<const bf16x8*>(pf[SCJ] + CUR * 32768 + 16384 + 4096); \
        oacc0 = __builtin_amdgcn_mfma_f32_32x32x16_bf16(va0, PAV, oacc0, 0, 0, 0); \
        oacc1 = __builtin_amdgcn_mfma_f32_32x32x16_bf16(va1, PAV, oacc1, 0, 0, 0); \
    }
    PV_STEP(0, pa0) PV_STEP(1, pa1) PV_STEP(2, pa2) PV_STEP(3, pa3)
#undef PV_STEP
    __builtin_amdgcn_s_setprio(0);
}

// ---------------- MFMA flash attention (unchanged) ----------------
__global__ __launch_bounds__(512, 4) void attn_mfma(const u16* __restrict__ q,
                                                    const u16* __restrict__ k,
                                                    const u16* __restrict__ vT,
                                                    u16* __restrict__ o) {
    __shared__ u16 smem[32768];

    const int tid  = threadIdx.x;
    const int wid  = tid >> 6;
    const int lane = tid & 63;
    const int l31  = lane & 31;
    const int hi   = lane >> 5;

    const int lin = blockIdx.x;
    const int r   = lin & 255;
    const int f   = lin >> 8;
    const int bh  = r & 63;
    const int e   = r >> 6;
    const int qb  = f ? (7 - e) : e;

    const int q0 = qb * 256;
    const size_t base = (size_t)bh * T_ * D_;
    const u16* kp  = k  + base;
    const u16* vtp = vT + (size_t)bh * D_ * T_;
    const int qglob = q0 + wid * 32 + l31;

    bf16x8 qf[4];
    {
        const u16* qp = q + base + (size_t)qglob * D_;
        #pragma unroll
        for (int kc = 0; kc < 4; ++kc)
            qf[kc] = *reinterpret_cast<const bf16x8*>(qp + kc * 16 + hi * 8);
    }

    const int rw = tid >> 3;
    const int cg = (tid & 7) ^ (rw & 7);
    const u16* gK = kp  + (size_t)rw * D_ + cg * 8;
    const u16* gV = vtp + (size_t)rw * T_ + cg * 8;

    u16* sbase = &smem[0];
    u16* dK = sbase + tid * 8;
    u16* dV = sbase + 8192 + tid * 8;

    const char* pf[4];
    #pragma unroll
    for (int j = 0; j < 4; ++j)
        pf[j] = reinterpret_cast<const char*>(sbase) + l31 * 128 + (((j * 2 + hi) ^ (l31 & 7)) << 4);

    float lrun = 0.f;
    f32x16 oacc0, oacc1, z16;
    #pragma unroll
    for (int rr = 0; rr < 16; ++rr) { oacc0[rr] = 0.f; oacc1[rr] = 0.f; z16[rr] = 0.f; }

    const int ntile  = 4 * qb + 4;
    const int diag_t = 4 * qb + (wid >> 1);
    const int relq   = 32 * (wid & 1) + l31;

#define STG(BUFU16)                                                                \
    {                                                                              \
        gload_lds16(gK, dK + (BUFU16)); gload_lds16(gV, dV + (BUFU16));            \
        gK += 64 * D_; gV += 64;                                                   \
    }

    STG(0);
    __syncthreads();

    for (int tt = 0; tt < ntile; tt += 2) {
        if (tt + 1 < ntile) STG(16384);
        if (tt <= diag_t)
            attn_tile<0>(pf, qf, z16, lrun, oacc0, oacc1, tt == diag_t, relq, hi);
        __syncthreads();
        if (tt + 2 < ntile) STG(0);
        if (tt + 1 <= diag_t)
            attn_tile<1>(pf, qf, z16, lrun, oacc0, oacc1, tt + 1 == diag_t, relq, hi);
        __syncthreads();
    }
#undef STG

    float linv = 1.f / lrun;
    float* ot = reinterpret_cast<float*>(sbase) + wid * 2048;
    #pragma unroll
    for (int rr = 0; rr < 16; ++rr) {
        int d0v = (rr & 3) + 8 * (rr >> 2) + 4 * hi;
        int d1v = d0v + 32;
        ot[l31 * 64 + (((d0v >> 2) ^ (l31 & 7)) << 2) + (d0v & 3)] = oacc0[rr] * linv;
        ot[l31 * 64 + (((d1v >> 2) ^ (l31 & 7)) << 2) + (d1v & 3)] = oacc1[rr] * linv;
    }

    const int b = bh >> 4, h = bh & 15;
    const int qrow = lane >> 1;
    const int d0 = (lane & 1) * 32;
    u16 tmp[32];
    #pragma unroll
    for (int i = 0; i < 8; ++i) {
        int g = ((d0 >> 2) + i) ^ (qrow & 7);
        float4 fv = *reinterpret_cast<const float4*>(&ot[qrow * 64 + (g << 2)]);
        tmp[i * 4 + 0] = f2bf(fv.x); tmp[i * 4 + 1] = f2bf(fv.y);
        tmp[i * 4 + 2] = f2bf(fv.z); tmp[i * 4 + 3] = f2bf(fv.w);
    }
    u16* orow = o + ((size_t)b * T_ + q0 + wid * 32 + qrow) * C_ + h * 64 + d0;
    #pragma unroll
    for (int j = 0; j < 4; ++j)
        *reinterpret_cast<ushort8*>(orow + j * 8) = *reinterpret_cast<ushort8*>(&tmp[j * 8]);
}

extern "C" void kernel_launch(void* const* d_in, const int* in_sizes, int n_in,
                              void* d_out, int out_size, void* d_ws, size_t ws_size,
                              hipStream_t stream) {
    const float* x  = (const float*)d_in[0];
    const float* Wq = (const float*)d_in[1];
    const float* Wk = (const float*)d_in[2];
    const float* Wv = (const float*)d_in[3];
    const float* Wp = (const float*)d_in[4];
    const float* bp = (const float*)d_in[5];
    float* out = (float*)d_out;

    const size_t E = (size_t)M_ * C_;
    u16* xb  = (u16*)d_ws;                   // reused as vT after qkv_gemm
    u16* qb  = xb  + E;
    u16* kb  = qb  + E;
    u16* vb  = kb  + E;
    u16* obf = vb  + E;
    u16* Wt  = obf + E;                      // [3072][1024]
    u16* Wpt = Wt  + (size_t)3072 * 1024;    // [1024][1024]
    u16* vTb = xb;                           // alias: xb dead after qkv_gemm

    cast_x<<<(E / 2048), 256, 0, stream>>>(x, xb);
    tw_qkv<<<dim3(16, 48), 256, 0, stream>>>(Wq, Wk, Wv, Wt);
    tw_p<<<dim3(16, 16), 256, 0, stream>>>(Wp, Wpt);

    qkv_gemm<<<dim3(M_ / 256, 3072 / 256), 512, 0, stream>>>(xb, Wt, qb, kb, vb);

    tv<<<dim3(T_ / 64, B_ * H_), 256, 0, stream>>>(vb, vTb);

    attn_mfma<<<dim3(512), 512, 0, stream>>>(qb, kb, vTb, obf);

    out_gemm<<<dim3(M_ / 256, C_ / 128), 256, 0, stream>>>(obf, Wpt, bp, out);
}

// Round 13
// 142.128 us; speedup vs baseline: 1.0789x; 1.0789x over previous
//
#include <hip/hip_runtime.h>
#include <hip/hip_bf16.h>

// B=4, T=2048, C=1024, H=16, D=64. fp32 in/out.
// prep (cast x + transpose weights, fused) -> qkv_gemm (gemm_core3; V written TRANSPOSED
// directly -> no tv kernel) -> attn (unchanged) -> out_gemm (unchanged).

#define B_ 4
#define T_ 2048
#define C_ 1024
#define H_ 16
#define D_ 64
#define M_ (B_*T_)      // 8192

typedef unsigned short u16;
typedef unsigned short ushort4v __attribute__((ext_vector_type(4)));
typedef unsigned short ushort8 __attribute__((ext_vector_type(8)));
typedef unsigned int uint4v __attribute__((ext_vector_type(4)));
typedef int int2v __attribute__((ext_vector_type(2)));
typedef __attribute__((ext_vector_type(8))) short bf16x8;
typedef __attribute__((ext_vector_type(16))) float f32x16;

__device__ __forceinline__ u16 f2bf(float f) {
    __hip_bfloat16 h = __float2bfloat16(f);
    return *reinterpret_cast<u16*>(&h);
}
__device__ __forceinline__ unsigned pkt(float lo, float hi2) {
    return __builtin_amdgcn_perm(__float_as_uint(hi2), __float_as_uint(lo), 0x07060302u);
}
__device__ __forceinline__ void gload_lds16(const void* g, void* lds) {
    __builtin_amdgcn_global_load_lds((const __attribute__((address_space(1))) unsigned int*)g,
                                     (__attribute__((address_space(3))) unsigned int*)lds, 16, 0, 0);
}
__device__ __forceinline__ int swz4(int r) { return (r ^ (r >> 2)) & 3; }   // 64B-row granule swizzle

// ---------------- fused prep: cast x -> bf16 | transpose+cast Wq/Wk/Wv | transpose Wp ----------------
__device__ __forceinline__ void ttile64(const float* __restrict__ in, int ldin,
                                        u16* __restrict__ out, int ldout, float scale) {
    __shared__ float t[64][65];
    const int tid = threadIdx.x;
    {
        int c = tid & 63, rr = tid >> 6;
        #pragma unroll
        for (int i = 0; i < 16; ++i) {
            int r = i * 4 + rr;
            t[r][c] = in[(size_t)r * ldin + c];
        }
    }
    __syncthreads();
    {
        int r2 = tid & 63, cg = tid >> 6;
        #pragma unroll
        for (int i = 0; i < 16; ++i) {
            int cc = i * 4 + cg;
            out[(size_t)cc * ldout + r2] = f2bf(t[r2][cc] * scale);
        }
    }
}

__global__ __launch_bounds__(256) void prep(const float* __restrict__ x,
                                            const float* __restrict__ Wq, const float* __restrict__ Wk,
                                            const float* __restrict__ Wv, const float* __restrict__ Wp,
                                            u16* __restrict__ xb, u16* __restrict__ Wt,
                                            u16* __restrict__ Wpt) {
    const int bid = blockIdx.x;
    if (bid < 4096) {                       // cast x (block-uniform branch)
        int i = (bid * 256 + threadIdx.x) * 8;
        float4 a = *reinterpret_cast<const float4*>(x + i);
        float4 b = *reinterpret_cast<const float4*>(x + i + 4);
        ushort8 o;
        o[0]=f2bf(a.x); o[1]=f2bf(a.y); o[2]=f2bf(a.z); o[3]=f2bf(a.w);
        o[4]=f2bf(b.x); o[5]=f2bf(b.y); o[6]=f2bf(b.z); o[7]=f2bf(b.w);
        *reinterpret_cast<ushort8*>(xb + i) = o;
    } else if (bid < 4096 + 768) {          // tw_qkv: Wt[which*1024 + h*64 + d][c], Wq pre-scaled
        int idx = bid - 4096;
        int r0 = (idx & 15) * 64, z = idx >> 4;
        int which = z >> 4, h = z & 15;
        const float* W = (which == 0 ? Wq : which == 1 ? Wk : Wv) + (size_t)h * C_ * D_;
        const float scale = (which == 0) ? 0.03125f * 1.4426950408889634f : 1.f;  // C^-0.5 * log2e
        ttile64(W + (size_t)r0 * D_, D_, Wt + (size_t)(which * 16 + h) * 64 * C_ + r0, C_, scale);
    } else {                                // tw_p
        int idx = bid - 4864;
        int r0 = (idx & 15) * 64, c0 = (idx >> 4) * 64;
        ttile64(Wp + (size_t)r0 * C_ + c0, C_, Wpt + (size_t)c0 * C_ + r0, C_, 1.f);
    }
}

// ---------------- GEMM core v3: BM=256 BN=128 BK=32, 4 waves (2Mx2N), wave tile 128x64 ----------------
// 32x32x16 MFMA. 2-deep dbuf 48KB -> 2 blocks/CU. Uniform 6 gloads/thread per K-tile ->
// exact per-wave vmcnt (steady 6, tail 0). Raw s_barrier + sched_barrier fences. (Round-11 core.)
__device__ __forceinline__ void gemm_core3(const u16* __restrict__ A, const u16* __restrict__ Bt,
                                           int m0, int n0, u16* lds, f32x16 (&acc)[4][2]) {
    const int tid = threadIdx.x;            // 256
    const int wid = tid >> 6, lane = tid & 63;
    const int l31 = lane & 31, hi = lane >> 5;
    const int wr = wid >> 1, wc = wid & 1;

    const u16* src[6];
    #pragma unroll
    for (int it = 0; it < 6; ++it) {
        int slot = it * 256 + tid;
        int row, g;
        const u16* base;
        if (it < 4) { row = slot >> 2; g = slot & 3; base = A + (size_t)(m0 + row) * C_; }
        else        { int s2 = slot - 1024; row = s2 >> 2; g = s2 & 3; base = Bt + (size_t)(n0 + row) * C_; }
        src[it] = base + ((g ^ swz4(row)) * 8);
    }

    const char* lb = reinterpret_cast<const char*>(lds);
    int aoff[2][4], boff[2][2];
    #pragma unroll
    for (int kk = 0; kk < 2; ++kk) {
        #pragma unroll
        for (int mt = 0; mt < 4; ++mt) {
            int row = wr * 128 + mt * 32 + l31;
            aoff[kk][mt] = row * 64 + (((kk * 2 + hi) ^ swz4(row)) & 3) * 16;
        }
        #pragma unroll
        for (int nt = 0; nt < 2; ++nt) {
            int row = wc * 64 + nt * 32 + l31;
            boff[kk][nt] = 16384 + row * 64 + (((kk * 2 + hi) ^ swz4(row)) & 3) * 16;
        }
    }

#define STG(BU16)                                                                   \
    {                                                                               \
        _Pragma("unroll")                                                           \
        for (int it = 0; it < 6; ++it) {                                            \
            gload_lds16(src[it], lds + (BU16) + (it * 256 + tid) * 8);              \
            src[it] += 32;                                                          \
        }                                                                           \
    }

    STG(0);
    STG(12288);

    #pragma unroll
    for (int t = 0; t < 32; ++t) {
        if (t < 31) { asm volatile("s_waitcnt vmcnt(6)" ::: "memory"); }
        else        { asm volatile("s_waitcnt vmcnt(0)" ::: "memory"); }
        __builtin_amdgcn_sched_barrier(0);
        __builtin_amdgcn_s_barrier();
        __builtin_amdgcn_sched_barrier(0);

        const char* lbuf = lb + (t & 1) * 24576;
        __builtin_amdgcn_s_setprio(1);
        #pragma unroll
        for (int kk = 0; kk < 2; ++kk) {
            bf16x8 bf0 = *reinterpret_cast<const bf16x8*>(lbuf + boff[kk][0]);
            bf16x8 bf1 = *reinterpret_cast<const bf16x8*>(lbuf + boff[kk][1]);
            #pragma unroll
            for (int mt = 0; mt < 4; ++mt) {
                bf16x8 af = *reinterpret_cast<const bf16x8*>(lbuf + aoff[kk][mt]);
                acc[mt][0] = __builtin_amdgcn_mfma_f32_32x32x16_bf16(af, bf0, acc[mt][0], 0, 0, 0);
                acc[mt][1] = __builtin_amdgcn_mfma_f32_32x32x16_bf16(af, bf1, acc[mt][1], 0, 0, 0);
            }
        }
        __builtin_amdgcn_s_setprio(0);
        __builtin_amdgcn_sched_barrier(0);
        __builtin_amdgcn_s_barrier();
        __builtin_amdgcn_sched_barrier(0);
        if (t + 2 < 32) STG((t & 1) * 12288);
    }
#undef STG
}

// ---------------- QKV GEMM: q,k -> [B,H,T,D]; V written TRANSPOSED -> vT [B,H,D,T] ----------------
__global__ __launch_bounds__(256, 2) void qkv_gemm(const u16* __restrict__ xb, const u16* __restrict__ Wt,
                                                   u16* __restrict__ q, u16* __restrict__ k,
                                                   u16* __restrict__ vT) {
    __shared__ u16 lds[2 * 12288];     // 48 KiB -> 2 blocks/CU
    f32x16 acc[4][2];
    #pragma unroll
    for (int i = 0; i < 4; ++i)
        #pragma unroll
        for (int j = 0; j < 2; ++j)
            #pragma unroll
            for (int r = 0; r < 16; ++r) acc[i][j][r] = 0.f;
    const int m0 = blockIdx.x * 256, n0 = blockIdx.y * 128;
    gemm_core3(xb, Wt, m0, n0, lds, acc);

    const int tid = threadIdx.x, wid = tid >> 6, lane = tid & 63;
    const int l31 = lane & 31, hi = lane >> 5;
    const int wr = wid >> 1, wc = wid & 1;
    #pragma unroll
    for (int mt = 0; mt < 4; ++mt) {
        #pragma unroll
        for (int nt = 0; nt < 2; ++nt) {
            int n = n0 + wc * 64 + nt * 32 + l31;
            int which = n >> 10, h = (n >> 6) & 15, d = n & 63;   // which block-uniform
            if (which < 2) {
                u16* dst = (which == 0 ? q : k);
                #pragma unroll
                for (int r = 0; r < 16; ++r) {
                    int m = m0 + wr * 128 + mt * 32 + (r & 3) + 8 * (r >> 2) + 4 * hi;
                    int b = m >> 11, t = m & (T_ - 1);
                    dst[((size_t)(b * H_ + h) * T_ + t) * D_ + d] = f2bf(acc[mt][nt][r]);
                }
            } else {
                // V transposed: vT[(b*H+h)*D + d][t]; 4 consecutive t per reg-quad -> 8B stores
                #pragma unroll
                for (int rq = 0; rq < 4; ++rq) {
                    int m = m0 + wr * 128 + mt * 32 + 8 * rq + 4 * hi;
                    int b = m >> 11, t = m & (T_ - 1);
                    ushort4v pk;
                    pk[0] = f2bf(acc[mt][nt][rq * 4 + 0]);
                    pk[1] = f2bf(acc[mt][nt][rq * 4 + 1]);
                    pk[2] = f2bf(acc[mt][nt][rq * 4 + 2]);
                    pk[3] = f2bf(acc[mt][nt][rq * 4 + 3]);
                    *reinterpret_cast<ushort4v*>(
                        vT + ((size_t)(b * H_ + h) * D_ + d) * T_ + t) = pk;
                }
            }
        }
    }
}

// ---------------- Output GEMM: [8192x1024]@[1024x1024] + bias -> fp32 ----------------
__global__ __launch_bounds__(256, 2) void out_gemm(const u16* __restrict__ ob, const u16* __restrict__ Wpt,
                                                   const float* __restrict__ bp, float* __restrict__ out) {
    __shared__ u16 lds[2 * 12288];
    f32x16 acc[4][2];
    #pragma unroll
    for (int i = 0; i < 4; ++i)
        #pragma unroll
        for (int j = 0; j < 2; ++j)
            #pragma unroll
            for (int r = 0; r < 16; ++r) acc[i][j][r] = 0.f;
    const int m0 = blockIdx.x * 256, n0 = blockIdx.y * 128;
    gemm_core3(ob, Wpt, m0, n0, lds, acc);

    const int tid = threadIdx.x, wid = tid >> 6, lane = tid & 63;
    const int l31 = lane & 31, hi = lane >> 5;
    const int wr = wid >> 1, wc = wid & 1;
    #pragma unroll
    for (int mt = 0; mt < 4; ++mt) {
        #pragma unroll
        for (int nt = 0; nt < 2; ++nt) {
            int n = n0 + wc * 64 + nt * 32 + l31;
            float bv = bp[n];
            #pragma unroll
            for (int r = 0; r < 16; ++r) {
                int m = m0 + wr * 128 + mt * 32 + (r & 3) + 8 * (r >> 2) + 4 * hi;
                out[(size_t)m * C_ + n] = acc[mt][nt][r] + bv;
            }
        }
    }
}

// ---------------- attn compute tile (unchanged from round 10/11) ----------------
template<int CUR>
__device__ __forceinline__ void attn_tile(const char* const (&pf)[4], const bf16x8 (&qf)[4],
                                          const f32x16& z16, float& lrun,
                                          f32x16& oacc0, f32x16& oacc1,
                                          bool isdiag, int relq, int hi) {
    f32x16 st0, st1;
    __builtin_amdgcn_s_setprio(1);
    {
        bf16x8 ka0 = *reinterpret_cast<const bf16x8*>(pf[0] + CUR * 32768);
        bf16x8 ka1 = *reinterpret_cast<const bf16x8*>(pf[0] + CUR * 32768 + 4096);
        st0 = __builtin_amdgcn_mfma_f32_32x32x16_bf16(ka0, qf[0], z16, 0, 0, 0);
        st1 = __builtin_amdgcn_mfma_f32_32x32x16_bf16(ka1, qf[0], z16, 0, 0, 0);
    }
    #pragma unroll
    for (int kc = 1; kc < 4; ++kc) {
        bf16x8 ka0 = *reinterpret_cast<const bf16x8*>(pf[kc] + CUR * 32768);
        bf16x8 ka1 = *reinterpret_cast<const bf16x8*>(pf[kc] + CUR * 32768 + 4096);
        st0 = __builtin_amdgcn_mfma_f32_32x32x16_bf16(ka0, qf[kc], st0, 0, 0, 0);
        st1 = __builtin_amdgcn_mfma_f32_32x32x16_bf16(ka1, qf[kc], st1, 0, 0, 0);
    }
    __builtin_amdgcn_s_setprio(0);

    if (isdiag) {
        #pragma unroll
        for (int rr = 0; rr < 16; ++rr) {
            int sl = (rr & 3) + 8 * (rr >> 2) + 4 * hi;
            if (sl > relq)      st0[rr] = -INFINITY;
            if (sl + 32 > relq) st1[rr] = -INFINITY;
        }
    }

    float rsum = 0.f;
    #pragma unroll
    for (int rr = 0; rr < 16; ++rr) {
        st0[rr] = __builtin_amdgcn_exp2f(st0[rr]);
        st1[rr] = __builtin_amdgcn_exp2f(st1[rr]);
        rsum += st0[rr] + st1[rr];
    }
    rsum += __shfl_xor(rsum, 32);
    lrun += rsum;

    bf16x8 pa0, pa1, pa2, pa3;
#if __has_builtin(__builtin_amdgcn_permlane32_swap)
#define MK_PA(PA, SV, RB)                                                          \
    {                                                                              \
        int X0 = (int)pkt(SV[RB + 0], SV[RB + 1]);                                 \
        int X1 = (int)pkt(SV[RB + 2], SV[RB + 3]);                                 \
        int Y0 = (int)pkt(SV[RB + 4], SV[RB + 5]);                                 \
        int Y1 = (int)pkt(SV[RB + 6], SV[RB + 7]);                                 \
        int2v r0 = __builtin_amdgcn_permlane32_swap(X0, Y0, false, false);         \
        int2v r1 = __builtin_amdgcn_permlane32_swap(X1, Y1, false, false);         \
        uint4v w; w[0] = (unsigned)r0[0]; w[1] = (unsigned)r1[0];                  \
        w[2] = (unsigned)r0[1]; w[3] = (unsigned)r1[1];                            \
        PA = __builtin_bit_cast(bf16x8, w);                                        \
    }
#else
#define MK_PA(PA, SV, RB)                                                          \
    {                                                                              \
        unsigned X0 = pkt(SV[RB + 0], SV[RB + 1]);                                 \
        unsigned X1 = pkt(SV[RB + 2], SV[RB + 3]);                                 \
        unsigned Y0 = pkt(SV[RB + 4], SV[RB + 5]);                                 \
        unsigned sX0 = __shfl_xor(X0, 32), sY0 = __shfl_xor(Y0, 32);               \
        unsigned Y1 = pkt(SV[RB + 6], SV[RB + 7]);                                 \
        unsigned sX1 = __shfl_xor(X1, 32), sY1 = __shfl_xor(Y1, 32);               \
        uint4v w;                                                                  \
        w[0] = hi ? sY0 : X0; w[1] = hi ? sY1 : X1;                                \
        w[2] = hi ? Y0 : sX0; w[3] = hi ? Y1 : sX1;                                \
        PA = __builtin_bit_cast(bf16x8, w);                                        \
    }
#endif
    MK_PA(pa0, st0, 0); MK_PA(pa1, st0, 8); MK_PA(pa2, st1, 0); MK_PA(pa3, st1, 8);
#undef MK_PA

    __builtin_amdgcn_s_setprio(1);
#define PV_STEP(SCJ, PAV)                                                          \
    {                                                                              \
        bf16x8 va0 = *reinterpret_cast<const bf16x8*>(pf[SCJ] + CUR * 32768 + 16384);        \
        bf16x8 va1 = *reinterpret_cast<const bf16x8*>(pf[SCJ] + CUR * 32768 + 16384 + 4096); \
        oacc0 = __builtin_amdgcn_mfma_f32_32x32x16_bf16(va0, PAV, oacc0, 0, 0, 0); \
        oacc1 = __builtin_amdgcn_mfma_f32_32x32x16_bf16(va1, PAV, oacc1, 0, 0, 0); \
    }
    PV_STEP(0, pa0) PV_STEP(1, pa1) PV_STEP(2, pa2) PV_STEP(3, pa3)
#undef PV_STEP
    __builtin_amdgcn_s_setprio(0);
}

// ---------------- MFMA flash attention (unchanged) ----------------
__global__ __launch_bounds__(512, 4) void attn_mfma(const u16* __restrict__ q,
                                                    const u16* __restrict__ k,
                                                    const u16* __restrict__ vT,
                                                    u16* __restrict__ o) {
    __shared__ u16 smem[32768];

    const int tid  = threadIdx.x;
    const int wid  = tid >> 6;
    const int lane = tid & 63;
    const int l31  = lane & 31;
    const int hi   = lane >> 5;

    const int lin = blockIdx.x;
    const int r   = lin & 255;
    const int f   = lin >> 8;
    const int bh  = r & 63;
    const int e   = r >> 6;
    const int qb  = f ? (7 - e) : e;

    const int q0 = qb * 256;
    const size_t base = (size_t)bh * T_ * D_;
    const u16* kp  = k  + base;
    const u16* vtp = vT + (size_t)bh * D_ * T_;
    const int qglob = q0 + wid * 32 + l31;

    bf16x8 qf[4];
    {
        const u16* qp = q + base + (size_t)qglob * D_;
        #pragma unroll
        for (int kc = 0; kc < 4; ++kc)
            qf[kc] = *reinterpret_cast<const bf16x8*>(qp + kc * 16 + hi * 8);
    }

    const int rw = tid >> 3;
    const int cg = (tid & 7) ^ (rw & 7);
    const u16* gK = kp  + (size_t)rw * D_ + cg * 8;
    const u16* gV = vtp + (size_t)rw * T_ + cg * 8;

    u16* sbase = &smem[0];
    u16* dK = sbase + tid * 8;
    u16* dV = sbase + 8192 + tid * 8;

    const char* pf[4];
    #pragma unroll
    for (int j = 0; j < 4; ++j)
        pf[j] = reinterpret_cast<const char*>(sbase) + l31 * 128 + (((j * 2 + hi) ^ (l31 & 7)) << 4);

    float lrun = 0.f;
    f32x16 oacc0, oacc1, z16;
    #pragma unroll
    for (int rr = 0; rr < 16; ++rr) { oacc0[rr] = 0.f; oacc1[rr] = 0.f; z16[rr] = 0.f; }

    const int ntile  = 4 * qb + 4;
    const int diag_t = 4 * qb + (wid >> 1);
    const int relq   = 32 * (wid & 1) + l31;

#define STG(BUFU16)                                                                \
    {                                                                              \
        gload_lds16(gK, dK + (BUFU16)); gload_lds16(gV, dV + (BUFU16));            \
        gK += 64 * D_; gV += 64;                                                   \
    }

    STG(0);
    __syncthreads();

    for (int tt = 0; tt < ntile; tt += 2) {
        if (tt + 1 < ntile) STG(16384);
        if (tt <= diag_t)
            attn_tile<0>(pf, qf, z16, lrun, oacc0, oacc1, tt == diag_t, relq, hi);
        __syncthreads();
        if (tt + 2 < ntile) STG(0);
        if (tt + 1 <= diag_t)
            attn_tile<1>(pf, qf, z16, lrun, oacc0, oacc1, tt + 1 == diag_t, relq, hi);
        __syncthreads();
    }
#undef STG

    float linv = 1.f / lrun;
    float* ot = reinterpret_cast<float*>(sbase) + wid * 2048;
    #pragma unroll
    for (int rr = 0; rr < 16; ++rr) {
        int d0v = (rr & 3) + 8 * (rr >> 2) + 4 * hi;
        int d1v = d0v + 32;
        ot[l31 * 64 + (((d0v >> 2) ^ (l31 & 7)) << 2) + (d0v & 3)] = oacc0[rr] * linv;
        ot[l31 * 64 + (((d1v >> 2) ^ (l31 & 7)) << 2) + (d1v & 3)] = oacc1[rr] * linv;
    }

    const int b = bh >> 4, h = bh & 15;
    const int qrow = lane >> 1;
    const int d0 = (lane & 1) * 32;
    u16 tmp[32];
    #pragma unroll
    for (int i = 0; i < 8; ++i) {
        int g = ((d0 >> 2) + i) ^ (qrow & 7);
        float4 fv = *reinterpret_cast<const float4*>(&ot[qrow * 64 + (g << 2)]);
        tmp[i * 4 + 0] = f2bf(fv.x); tmp[i * 4 + 1] = f2bf(fv.y);
        tmp[i * 4 + 2] = f2bf(fv.z); tmp[i * 4 + 3] = f2bf(fv.w);
    }
    u16* orow = o + ((size_t)b * T_ + q0 + wid * 32 + qrow) * C_ + h * 64 + d0;
    #pragma unroll
    for (int j = 0; j < 4; ++j)
        *reinterpret_cast<ushort8*>(orow + j * 8) = *reinterpret_cast<ushort8*>(&tmp[j * 8]);
}

extern "C" void kernel_launch(void* const* d_in, const int* in_sizes, int n_in,
                              void* d_out, int out_size, void* d_ws, size_t ws_size,
                              hipStream_t stream) {
    const float* x  = (const float*)d_in[0];
    const float* Wq = (const float*)d_in[1];
    const float* Wk = (const float*)d_in[2];
    const float* Wv = (const float*)d_in[3];
    const float* Wp = (const float*)d_in[4];
    const float* bp = (const float*)d_in[5];
    float* out = (float*)d_out;

    const size_t E = (size_t)M_ * C_;
    u16* xb  = (u16*)d_ws;
    u16* qb  = xb  + E;
    u16* kb  = qb  + E;
    u16* vTb = kb  + E;                      // V stored transposed [B,H,D,T] by qkv_gemm
    u16* obf = vTb + E;
    u16* Wt  = obf + E;                      // [3072][1024]
    u16* Wpt = Wt  + (size_t)3072 * 1024;    // [1024][1024]

    // fused prep: blocks [0,4096) cast x, [4096,4864) tw_qkv, [4864,5120) tw_p
    prep<<<dim3(5120), 256, 0, stream>>>(x, Wq, Wk, Wv, Wp, xb, Wt, Wpt);

    qkv_gemm<<<dim3(M_ / 256, 3072 / 128), 256, 0, stream>>>(xb, Wt, qb, kb, vTb);

    attn_mfma<<<dim3(512), 512, 0, stream>>>(qb, kb, vTb, obf);

    out_gemm<<<dim3(M_ / 256, C_ / 128), 256, 0, stream>>>(obf, Wpt, bp, out);
}

// Round 14
// 141.601 us; speedup vs baseline: 1.0829x; 1.0037x over previous
//
#include <hip/hip_runtime.h>
#include <hip/hip_bf16.h>

// B=4, T=2048, C=1024, H=16, D=64. fp32 in/out.
// prep (fused cast/transpose) -> qkv_gemm (gemm_core3, V written transposed) ->
// attn (XCD-locality block decode: same-bh pairs per CU, 8 bh per XCD) -> out_gemm.

#define B_ 4
#define T_ 2048
#define C_ 1024
#define H_ 16
#define D_ 64
#define M_ (B_*T_)      // 8192

typedef unsigned short u16;
typedef unsigned short ushort4v __attribute__((ext_vector_type(4)));
typedef unsigned short ushort8 __attribute__((ext_vector_type(8)));
typedef unsigned int uint4v __attribute__((ext_vector_type(4)));
typedef int int2v __attribute__((ext_vector_type(2)));
typedef __attribute__((ext_vector_type(8))) short bf16x8;
typedef __attribute__((ext_vector_type(16))) float f32x16;

__device__ __forceinline__ u16 f2bf(float f) {
    __hip_bfloat16 h = __float2bfloat16(f);
    return *reinterpret_cast<u16*>(&h);
}
__device__ __forceinline__ unsigned pkt(float lo, float hi2) {
    return __builtin_amdgcn_perm(__float_as_uint(hi2), __float_as_uint(lo), 0x07060302u);
}
__device__ __forceinline__ void gload_lds16(const void* g, void* lds) {
    __builtin_amdgcn_global_load_lds((const __attribute__((address_space(1))) unsigned int*)g,
                                     (__attribute__((address_space(3))) unsigned int*)lds, 16, 0, 0);
}
__device__ __forceinline__ int swz4(int r) { return (r ^ (r >> 2)) & 3; }   // 64B-row granule swizzle

// ---------------- fused prep: cast x -> bf16 | transpose+cast Wq/Wk/Wv | transpose Wp ----------------
__device__ __forceinline__ void ttile64(const float* __restrict__ in, int ldin,
                                        u16* __restrict__ out, int ldout, float scale) {
    __shared__ float t[64][65];
    const int tid = threadIdx.x;
    {
        int c = tid & 63, rr = tid >> 6;
        #pragma unroll
        for (int i = 0; i < 16; ++i) {
            int r = i * 4 + rr;
            t[r][c] = in[(size_t)r * ldin + c];
        }
    }
    __syncthreads();
    {
        int r2 = tid & 63, cg = tid >> 6;
        #pragma unroll
        for (int i = 0; i < 16; ++i) {
            int cc = i * 4 + cg;
            out[(size_t)cc * ldout + r2] = f2bf(t[r2][cc] * scale);
        }
    }
}

__global__ __launch_bounds__(256) void prep(const float* __restrict__ x,
                                            const float* __restrict__ Wq, const float* __restrict__ Wk,
                                            const float* __restrict__ Wv, const float* __restrict__ Wp,
                                            u16* __restrict__ xb, u16* __restrict__ Wt,
                                            u16* __restrict__ Wpt) {
    const int bid = blockIdx.x;
    if (bid < 4096) {                       // cast x (block-uniform branch)
        int i = (bid * 256 + threadIdx.x) * 8;
        float4 a = *reinterpret_cast<const float4*>(x + i);
        float4 b = *reinterpret_cast<const float4*>(x + i + 4);
        ushort8 o;
        o[0]=f2bf(a.x); o[1]=f2bf(a.y); o[2]=f2bf(a.z); o[3]=f2bf(a.w);
        o[4]=f2bf(b.x); o[5]=f2bf(b.y); o[6]=f2bf(b.z); o[7]=f2bf(b.w);
        *reinterpret_cast<ushort8*>(xb + i) = o;
    } else if (bid < 4096 + 768) {          // tw_qkv: Wt[which*1024 + h*64 + d][c], Wq pre-scaled
        int idx = bid - 4096;
        int r0 = (idx & 15) * 64, z = idx >> 4;
        int which = z >> 4, h = z & 15;
        const float* W = (which == 0 ? Wq : which == 1 ? Wk : Wv) + (size_t)h * C_ * D_;
        const float scale = (which == 0) ? 0.03125f * 1.4426950408889634f : 1.f;  // C^-0.5 * log2e
        ttile64(W + (size_t)r0 * D_, D_, Wt + (size_t)(which * 16 + h) * 64 * C_ + r0, C_, scale);
    } else {                                // tw_p
        int idx = bid - 4864;
        int r0 = (idx & 15) * 64, c0 = (idx >> 4) * 64;
        ttile64(Wp + (size_t)r0 * C_ + c0, C_, Wpt + (size_t)c0 * C_ + r0, C_, 1.f);
    }
}

// ---------------- GEMM core v3: BM=256 BN=128 BK=32, 4 waves (2Mx2N), wave tile 128x64 ----------------
__device__ __forceinline__ void gemm_core3(const u16* __restrict__ A, const u16* __restrict__ Bt,
                                           int m0, int n0, u16* lds, f32x16 (&acc)[4][2]) {
    const int tid = threadIdx.x;            // 256
    const int wid = tid >> 6, lane = tid & 63;
    const int l31 = lane & 31, hi = lane >> 5;
    const int wr = wid >> 1, wc = wid & 1;

    const u16* src[6];
    #pragma unroll
    for (int it = 0; it < 6; ++it) {
        int slot = it * 256 + tid;
        int row, g;
        const u16* base;
        if (it < 4) { row = slot >> 2; g = slot & 3; base = A + (size_t)(m0 + row) * C_; }
        else        { int s2 = slot - 1024; row = s2 >> 2; g = s2 & 3; base = Bt + (size_t)(n0 + row) * C_; }
        src[it] = base + ((g ^ swz4(row)) * 8);
    }

    const char* lb = reinterpret_cast<const char*>(lds);
    int aoff[2][4], boff[2][2];
    #pragma unroll
    for (int kk = 0; kk < 2; ++kk) {
        #pragma unroll
        for (int mt = 0; mt < 4; ++mt) {
            int row = wr * 128 + mt * 32 + l31;
            aoff[kk][mt] = row * 64 + (((kk * 2 + hi) ^ swz4(row)) & 3) * 16;
        }
        #pragma unroll
        for (int nt = 0; nt < 2; ++nt) {
            int row = wc * 64 + nt * 32 + l31;
            boff[kk][nt] = 16384 + row * 64 + (((kk * 2 + hi) ^ swz4(row)) & 3) * 16;
        }
    }

#define STG(BU16)                                                                   \
    {                                                                               \
        _Pragma("unroll")                                                           \
        for (int it = 0; it < 6; ++it) {                                            \
            gload_lds16(src[it], lds + (BU16) + (it * 256 + tid) * 8);              \
            src[it] += 32;                                                          \
        }                                                                           \
    }

    STG(0);
    STG(12288);

    #pragma unroll
    for (int t = 0; t < 32; ++t) {
        if (t < 31) { asm volatile("s_waitcnt vmcnt(6)" ::: "memory"); }
        else        { asm volatile("s_waitcnt vmcnt(0)" ::: "memory"); }
        __builtin_amdgcn_sched_barrier(0);
        __builtin_amdgcn_s_barrier();
        __builtin_amdgcn_sched_barrier(0);

        const char* lbuf = lb + (t & 1) * 24576;
        __builtin_amdgcn_s_setprio(1);
        #pragma unroll
        for (int kk = 0; kk < 2; ++kk) {
            bf16x8 bf0 = *reinterpret_cast<const bf16x8*>(lbuf + boff[kk][0]);
            bf16x8 bf1 = *reinterpret_cast<const bf16x8*>(lbuf + boff[kk][1]);
            #pragma unroll
            for (int mt = 0; mt < 4; ++mt) {
                bf16x8 af = *reinterpret_cast<const bf16x8*>(lbuf + aoff[kk][mt]);
                acc[mt][0] = __builtin_amdgcn_mfma_f32_32x32x16_bf16(af, bf0, acc[mt][0], 0, 0, 0);
                acc[mt][1] = __builtin_amdgcn_mfma_f32_32x32x16_bf16(af, bf1, acc[mt][1], 0, 0, 0);
            }
        }
        __builtin_amdgcn_s_setprio(0);
        __builtin_amdgcn_sched_barrier(0);
        __builtin_amdgcn_s_barrier();
        __builtin_amdgcn_sched_barrier(0);
        if (t + 2 < 32) STG((t & 1) * 12288);
    }
#undef STG
}

// ---------------- QKV GEMM: q,k -> [B,H,T,D]; V written TRANSPOSED -> vT [B,H,D,T] ----------------
__global__ __launch_bounds__(256, 2) void qkv_gemm(const u16* __restrict__ xb, const u16* __restrict__ Wt,
                                                   u16* __restrict__ q, u16* __restrict__ k,
                                                   u16* __restrict__ vT) {
    __shared__ u16 lds[2 * 12288];     // 48 KiB -> 2 blocks/CU
    f32x16 acc[4][2];
    #pragma unroll
    for (int i = 0; i < 4; ++i)
        #pragma unroll
        for (int j = 0; j < 2; ++j)
            #pragma unroll
            for (int r = 0; r < 16; ++r) acc[i][j][r] = 0.f;
    const int m0 = blockIdx.x * 256, n0 = blockIdx.y * 128;
    gemm_core3(xb, Wt, m0, n0, lds, acc);

    const int tid = threadIdx.x, wid = tid >> 6, lane = tid & 63;
    const int l31 = lane & 31, hi = lane >> 5;
    const int wr = wid >> 1, wc = wid & 1;
    #pragma unroll
    for (int mt = 0; mt < 4; ++mt) {
        #pragma unroll
        for (int nt = 0; nt < 2; ++nt) {
            int n = n0 + wc * 64 + nt * 32 + l31;
            int which = n >> 10, h = (n >> 6) & 15, d = n & 63;   // which block-uniform
            if (which < 2) {
                u16* dst = (which == 0 ? q : k);
                #pragma unroll
                for (int r = 0; r < 16; ++r) {
                    int m = m0 + wr * 128 + mt * 32 + (r & 3) + 8 * (r >> 2) + 4 * hi;
                    int b = m >> 11, t = m & (T_ - 1);
                    dst[((size_t)(b * H_ + h) * T_ + t) * D_ + d] = f2bf(acc[mt][nt][r]);
                }
            } else {
                // V transposed: vT[(b*H+h)*D + d][t]; 4 consecutive t per reg-quad -> 8B stores
                #pragma unroll
                for (int rq = 0; rq < 4; ++rq) {
                    int m = m0 + wr * 128 + mt * 32 + 8 * rq + 4 * hi;
                    int b = m >> 11, t = m & (T_ - 1);
                    ushort4v pk;
                    pk[0] = f2bf(acc[mt][nt][rq * 4 + 0]);
                    pk[1] = f2bf(acc[mt][nt][rq * 4 + 1]);
                    pk[2] = f2bf(acc[mt][nt][rq * 4 + 2]);
                    pk[3] = f2bf(acc[mt][nt][rq * 4 + 3]);
                    *reinterpret_cast<ushort4v*>(
                        vT + ((size_t)(b * H_ + h) * D_ + d) * T_ + t) = pk;
                }
            }
        }
    }
}

// ---------------- Output GEMM: [8192x1024]@[1024x1024] + bias -> fp32 ----------------
__global__ __launch_bounds__(256, 2) void out_gemm(const u16* __restrict__ ob, const u16* __restrict__ Wpt,
                                                   const float* __restrict__ bp, float* __restrict__ out) {
    __shared__ u16 lds[2 * 12288];
    f32x16 acc[4][2];
    #pragma unroll
    for (int i = 0; i < 4; ++i)
        #pragma unroll
        for (int j = 0; j < 2; ++j)
            #pragma unroll
            for (int r = 0; r < 16; ++r) acc[i][j][r] = 0.f;
    const int m0 = blockIdx.x * 256, n0 = blockIdx.y * 128;
    gemm_core3(ob, Wpt, m0, n0, lds, acc);

    const int tid = threadIdx.x, wid = tid >> 6, lane = tid & 63;
    const int l31 = lane & 31, hi = lane >> 5;
    const int wr = wid >> 1, wc = wid & 1;
    #pragma unroll
    for (int mt = 0; mt < 4; ++mt) {
        #pragma unroll
        for (int nt = 0; nt < 2; ++nt) {
            int n = n0 + wc * 64 + nt * 32 + l31;
            float bv = bp[n];
            #pragma unroll
            for (int r = 0; r < 16; ++r) {
                int m = m0 + wr * 128 + mt * 32 + (r & 3) + 8 * (r >> 2) + 4 * hi;
                out[(size_t)m * C_ + n] = acc[mt][nt][r] + bv;
            }
        }
    }
}

// ---------------- attn compute tile (unchanged) ----------------
template<int CUR>
__device__ __forceinline__ void attn_tile(const char* const (&pf)[4], const bf16x8 (&qf)[4],
                                          const f32x16& z16, float& lrun,
                                          f32x16& oacc0, f32x16& oacc1,
                                          bool isdiag, int relq, int hi) {
    f32x16 st0, st1;
    __builtin_amdgcn_s_setprio(1);
    {
        bf16x8 ka0 = *reinterpret_cast<const bf16x8*>(pf[0] + CUR * 32768);
        bf16x8 ka1 = *reinterpret_cast<const bf16x8*>(pf[0] + CUR * 32768 + 4096);
        st0 = __builtin_amdgcn_mfma_f32_32x32x16_bf16(ka0, qf[0], z16, 0, 0, 0);
        st1 = __builtin_amdgcn_mfma_f32_32x32x16_bf16(ka1, qf[0], z16, 0, 0, 0);
    }
    #pragma unroll
    for (int kc = 1; kc < 4; ++kc) {
        bf16x8 ka0 = *reinterpret_cast<const bf16x8*>(pf[kc] + CUR * 32768);
        bf16x8 ka1 = *reinterpret_cast<const bf16x8*>(pf[kc] + CUR * 32768 + 4096);
        st0 = __builtin_amdgcn_mfma_f32_32x32x16_bf16(ka0, qf[kc], st0, 0, 0, 0);
        st1 = __builtin_amdgcn_mfma_f32_32x32x16_bf16(ka1, qf[kc], st1, 0, 0, 0);
    }
    __builtin_amdgcn_s_setprio(0);

    if (isdiag) {
        #pragma unroll
        for (int rr = 0; rr < 16; ++rr) {
            int sl = (rr & 3) + 8 * (rr >> 2) + 4 * hi;
            if (sl > relq)      st0[rr] = -INFINITY;
            if (sl + 32 > relq) st1[rr] = -INFINITY;
        }
    }

    float rsum = 0.f;
    #pragma unroll
    for (int rr = 0; rr < 16; ++rr) {
        st0[rr] = __builtin_amdgcn_exp2f(st0[rr]);
        st1[rr] = __builtin_amdgcn_exp2f(st1[rr]);
        rsum += st0[rr] + st1[rr];
    }
    rsum += __shfl_xor(rsum, 32);
    lrun += rsum;

    bf16x8 pa0, pa1, pa2, pa3;
#if __has_builtin(__builtin_amdgcn_permlane32_swap)
#define MK_PA(PA, SV, RB)                                                          \
    {                                                                              \
        int X0 = (int)pkt(SV[RB + 0], SV[RB + 1]);                                 \
        int X1 = (int)pkt(SV[RB + 2], SV[RB + 3]);                                 \
        int Y0 = (int)pkt(SV[RB + 4], SV[RB + 5]);                                 \
        int Y1 = (int)pkt(SV[RB + 6], SV[RB + 7]);                                 \
        int2v r0 = __builtin_amdgcn_permlane32_swap(X0, Y0, false, false);         \
        int2v r1 = __builtin_amdgcn_permlane32_swap(X1, Y1, false, false);         \
        uint4v w; w[0] = (unsigned)r0[0]; w[1] = (unsigned)r1[0];                  \
        w[2] = (unsigned)r0[1]; w[3] = (unsigned)r1[1];                            \
        PA = __builtin_bit_cast(bf16x8, w);                                        \
    }
#else
#define MK_PA(PA, SV, RB)                                                          \
    {                                                                              \
        unsigned X0 = pkt(SV[RB + 0], SV[RB + 1]);                                 \
        unsigned X1 = pkt(SV[RB + 2], SV[RB + 3]);                                 \
        unsigned Y0 = pkt(SV[RB + 4], SV[RB + 5]);                                 \
        unsigned sX0 = __shfl_xor(X0, 32), sY0 = __shfl_xor(Y0, 32);               \
        unsigned Y1 = pkt(SV[RB + 6], SV[RB + 7]);                                 \
        unsigned sX1 = __shfl_xor(X1, 32), sY1 = __shfl_xor(Y1, 32);               \
        uint4v w;                                                                  \
        w[0] = hi ? sY0 : X0; w[1] = hi ? sY1 : X1;                                \
        w[2] = hi ? Y0 : sX0; w[3] = hi ? Y1 : sX1;                                \
        PA = __builtin_bit_cast(bf16x8, w);                                        \
    }
#endif
    MK_PA(pa0, st0, 0); MK_PA(pa1, st0, 8); MK_PA(pa2, st1, 0); MK_PA(pa3, st1, 8);
#undef MK_PA

    __builtin_amdgcn_s_setprio(1);
#define PV_STEP(SCJ, PAV)                                                          \
    {                                                                              \
        bf16x8 va0 = *reinterpret_cast<const bf16x8*>(pf[SCJ] + CUR * 32768 + 16384);        \
        bf16x8 va1 = *reinterpret_cast<const bf16x8*>(pf[SCJ] + CUR * 32768 + 16384 + 4096); \
        oacc0 = __builtin_amdgcn_mfma_f32_32x32x16_bf16(va0, PAV, oacc0, 0, 0, 0); \
        oacc1 = __builtin_amdgcn_mfma_f32_32x32x16_bf16(va1, PAV, oacc1, 0, 0, 0); \
    }
    PV_STEP(0, pa0) PV_STEP(1, pa1) PV_STEP(2, pa2) PV_STEP(3, pa3)
#undef PV_STEP
    __builtin_amdgcn_s_setprio(0);
}

// ---------------- MFMA flash attention: XCD-locality decode ----------------
// lin = f*256 + i*8 + xcd (dispatch round-robins lin across XCDs -> xcd = lin&7).
// bh = xcd*8 + (i&7): each XCD sees only 8 heads (K+V = 4MB = its L2).
// Each CU gets lin=r and lin=r+256 -> same bh, qb = {e, 7-e}: 36 tiles/CU constant,
// partner block's K/V reads hit L1/L2.
__global__ __launch_bounds__(512, 4) void attn_mfma(const u16* __restrict__ q,
                                                    const u16* __restrict__ k,
                                                    const u16* __restrict__ vT,
                                                    u16* __restrict__ o) {
    __shared__ u16 smem[32768];

    const int tid  = threadIdx.x;
    const int wid  = tid >> 6;
    const int lane = tid & 63;
    const int l31  = lane & 31;
    const int hi   = lane >> 5;

    const int lin = blockIdx.x;       // 0..511
    const int xcd = lin & 7;
    const int i   = (lin >> 3) & 31;
    const int f   = lin >> 8;
    const int bh  = xcd * 8 + (i & 7);
    const int e   = i >> 3;           // 0..3
    const int qb  = f ? (7 - e) : e;

    const int q0 = qb * 256;
    const size_t base = (size_t)bh * T_ * D_;
    const u16* kp  = k  + base;
    const u16* vtp = vT + (size_t)bh * D_ * T_;
    const int qglob = q0 + wid * 32 + l31;

    bf16x8 qf[4];
    {
        const u16* qp = q + base + (size_t)qglob * D_;
        #pragma unroll
        for (int kc = 0; kc < 4; ++kc)
            qf[kc] = *reinterpret_cast<const bf16x8*>(qp + kc * 16 + hi * 8);
    }

    const int rw = tid >> 3;
    const int cg = (tid & 7) ^ (rw & 7);
    const u16* gK = kp  + (size_t)rw * D_ + cg * 8;
    const u16* gV = vtp + (size_t)rw * T_ + cg * 8;

    u16* sbase = &smem[0];
    u16* dK = sbase + tid * 8;
    u16* dV = sbase + 8192 + tid * 8;

    const char* pf[4];
    #pragma unroll
    for (int j = 0; j < 4; ++j)
        pf[j] = reinterpret_cast<const char*>(sbase) + l31 * 128 + (((j * 2 + hi) ^ (l31 & 7)) << 4);

    float lrun = 0.f;
    f32x16 oacc0, oacc1, z16;
    #pragma unroll
    for (int rr = 0; rr < 16; ++rr) { oacc0[rr] = 0.f; oacc1[rr] = 0.f; z16[rr] = 0.f; }

    const int ntile  = 4 * qb + 4;
    const int diag_t = 4 * qb + (wid >> 1);
    const int relq   = 32 * (wid & 1) + l31;

#define STG(BUFU16)                                                                \
    {                                                                              \
        gload_lds16(gK, dK + (BUFU16)); gload_lds16(gV, dV + (BUFU16));            \
        gK += 64 * D_; gV += 64;                                                   \
    }

    STG(0);
    __syncthreads();

    for (int tt = 0; tt < ntile; tt += 2) {
        if (tt + 1 < ntile) STG(16384);
        if (tt <= diag_t)
            attn_tile<0>(pf, qf, z16, lrun, oacc0, oacc1, tt == diag_t, relq, hi);
        __syncthreads();
        if (tt + 2 < ntile) STG(0);
        if (tt + 1 <= diag_t)
            attn_tile<1>(pf, qf, z16, lrun, oacc0, oacc1, tt + 1 == diag_t, relq, hi);
        __syncthreads();
    }
#undef STG

    float linv = 1.f / lrun;
    float* ot = reinterpret_cast<float*>(sbase) + wid * 2048;
    #pragma unroll
    for (int rr = 0; rr < 16; ++rr) {
        int d0v = (rr & 3) + 8 * (rr >> 2) + 4 * hi;
        int d1v = d0v + 32;
        ot[l31 * 64 + (((d0v >> 2) ^ (l31 & 7)) << 2) + (d0v & 3)] = oacc0[rr] * linv;
        ot[l31 * 64 + (((d1v >> 2) ^ (l31 & 7)) << 2) + (d1v & 3)] = oacc1[rr] * linv;
    }

    const int b = bh >> 4, h = bh & 15;
    const int qrow = lane >> 1;
    const int d0 = (lane & 1) * 32;
    u16 tmp[32];
    #pragma unroll
    for (int i2 = 0; i2 < 8; ++i2) {
        int g = ((d0 >> 2) + i2) ^ (qrow & 7);
        float4 fv = *reinterpret_cast<const float4*>(&ot[qrow * 64 + (g << 2)]);
        tmp[i2 * 4 + 0] = f2bf(fv.x); tmp[i2 * 4 + 1] = f2bf(fv.y);
        tmp[i2 * 4 + 2] = f2bf(fv.z); tmp[i2 * 4 + 3] = f2bf(fv.w);
    }
    u16* orow = o + ((size_t)b * T_ + q0 + wid * 32 + qrow) * C_ + h * 64 + d0;
    #pragma unroll
    for (int j = 0; j < 4; ++j)
        *reinterpret_cast<ushort8*>(orow + j * 8) = *reinterpret_cast<ushort8*>(&tmp[j * 8]);
}

extern "C" void kernel_launch(void* const* d_in, const int* in_sizes, int n_in,
                              void* d_out, int out_size, void* d_ws, size_t ws_size,
                              hipStream_t stream) {
    const float* x  = (const float*)d_in[0];
    const float* Wq = (const float*)d_in[1];
    const float* Wk = (const float*)d_in[2];
    const float* Wv = (const float*)d_in[3];
    const float* Wp = (const float*)d_in[4];
    const float* bp = (const float*)d_in[5];
    float* out = (float*)d_out;

    const size_t E = (size_t)M_ * C_;
    u16* xb  = (u16*)d_ws;
    u16* qb  = xb  + E;
    u16* kb  = qb  + E;
    u16* vTb = kb  + E;                      // V stored transposed [B,H,D,T] by qkv_gemm
    u16* obf = vTb + E;
    u16* Wt  = obf + E;                      // [3072][1024]
    u16* Wpt = Wt  + (size_t)3072 * 1024;    // [1024][1024]

    prep<<<dim3(5120), 256, 0, stream>>>(x, Wq, Wk, Wv, Wp, xb, Wt, Wpt);

    qkv_gemm<<<dim3(M_ / 256, 3072 / 128), 256, 0, stream>>>(xb, Wt, qb, kb, vTb);

    attn_mfma<<<dim3(512), 512, 0, stream>>>(qb, kb, vTb, obf);

    out_gemm<<<dim3(M_ / 256, C_ / 128), 256, 0, stream>>>(obf, Wpt, bp, out);
}

// Round 15
// 138.762 us; speedup vs baseline: 1.1050x; 1.0205x over previous
//
#include <hip/hip_runtime.h>
#include <hip/hip_bf16.h>

// B=4, T=2048, C=1024, H=16, D=64. fp32 in/out.
// prep (fused cast/transpose) -> qkv_gemm (slab-phased core, counted vmcnt never-drain,
// V written transposed) -> attn (XCD-locality decode) -> out_gemm (same core + bias).

#define B_ 4
#define T_ 2048
#define C_ 1024
#define H_ 16
#define D_ 64
#define M_ (B_*T_)      // 8192

typedef unsigned short u16;
typedef unsigned short ushort4v __attribute__((ext_vector_type(4)));
typedef unsigned short ushort8 __attribute__((ext_vector_type(8)));
typedef unsigned int uint4v __attribute__((ext_vector_type(4)));
typedef int int2v __attribute__((ext_vector_type(2)));
typedef __attribute__((ext_vector_type(8))) short bf16x8;
typedef __attribute__((ext_vector_type(4))) float f32x4;
typedef __attribute__((ext_vector_type(16))) float f32x16;

__device__ __forceinline__ u16 f2bf(float f) {
    __hip_bfloat16 h = __float2bfloat16(f);
    return *reinterpret_cast<u16*>(&h);
}
__device__ __forceinline__ unsigned pkt(float lo, float hi2) {
    return __builtin_amdgcn_perm(__float_as_uint(hi2), __float_as_uint(lo), 0x07060302u);
}
__device__ __forceinline__ void gload_lds16(const void* g, void* lds) {
    __builtin_amdgcn_global_load_lds((const __attribute__((address_space(1))) unsigned int*)g,
                                     (__attribute__((address_space(3))) unsigned int*)lds, 16, 0, 0);
}
__device__ __forceinline__ int swz4(int r) { return (r ^ (r >> 2)) & 3; }   // 64B-row granule swizzle

// ---------------- fused prep: cast x -> bf16 | transpose+cast Wq/Wk/Wv | transpose Wp ----------------
__device__ __forceinline__ void ttile64(const float* __restrict__ in, int ldin,
                                        u16* __restrict__ out, int ldout, float scale) {
    __shared__ float t[64][65];
    const int tid = threadIdx.x;
    {
        int c = tid & 63, rr = tid >> 6;
        #pragma unroll
        for (int i = 0; i < 16; ++i) {
            int r = i * 4 + rr;
            t[r][c] = in[(size_t)r * ldin + c];
        }
    }
    __syncthreads();
    {
        int r2 = tid & 63, cg = tid >> 6;
        #pragma unroll
        for (int i = 0; i < 16; ++i) {
            int cc = i * 4 + cg;
            out[(size_t)cc * ldout + r2] = f2bf(t[r2][cc] * scale);
        }
    }
}

__global__ __launch_bounds__(256) void prep(const float* __restrict__ x,
                                            const float* __restrict__ Wq, const float* __restrict__ Wk,
                                            const float* __restrict__ Wv, const float* __restrict__ Wp,
                                            u16* __restrict__ xb, u16* __restrict__ Wt,
                                            u16* __restrict__ Wpt) {
    const int bid = blockIdx.x;
    if (bid < 4096) {
        int i = (bid * 256 + threadIdx.x) * 8;
        float4 a = *reinterpret_cast<const float4*>(x + i);
        float4 b = *reinterpret_cast<const float4*>(x + i + 4);
        ushort8 o;
        o[0]=f2bf(a.x); o[1]=f2bf(a.y); o[2]=f2bf(a.z); o[3]=f2bf(a.w);
        o[4]=f2bf(b.x); o[5]=f2bf(b.y); o[6]=f2bf(b.z); o[7]=f2bf(b.w);
        *reinterpret_cast<ushort8*>(xb + i) = o;
    } else if (bid < 4096 + 768) {
        int idx = bid - 4096;
        int r0 = (idx & 15) * 64, z = idx >> 4;
        int which = z >> 4, h = z & 15;
        const float* W = (which == 0 ? Wq : which == 1 ? Wk : Wv) + (size_t)h * C_ * D_;
        const float scale = (which == 0) ? 0.03125f * 1.4426950408889634f : 1.f;  // C^-0.5 * log2e
        ttile64(W + (size_t)r0 * D_, D_, Wt + (size_t)(which * 16 + h) * 64 * C_ + r0, C_, scale);
    } else {
        int idx = bid - 4864;
        int r0 = (idx & 15) * 64, c0 = (idx >> 4) * 64;
        ttile64(Wp + (size_t)r0 * C_ + c0, C_, Wpt + (size_t)c0 * C_ + r0, C_, 1.f);
    }
}

// ---------------- slab-phased GEMM core ----------------
// BM=256 BN=128 BK=64 (2 k-slabs of 32). 8 waves (4M x 2N), wave tile 64x64, 16x16x32 MFMA.
// LDS 96KB: buf d(2) x sec c(2) x [A 256x32 16KB | B 128x32 8KB]; 64B rows, swz4 granules.
// Per phase: counted vmcnt(6) (3 loads/slab/thread, 2 newer slabs in flight) -> barrier ->
// stage next slab -> ds_read+16 MFMA. Never drains to 0 until the tail (vmcnt in-order retire).
__device__ __forceinline__ void gemm_slab(const u16* __restrict__ A, const u16* __restrict__ Bt,
                                          int m0, int n0, u16* lds, f32x4 (&acc)[4][4]) {
    const int tid = threadIdx.x;            // 512
    const int wid = tid >> 6, lane = tid & 63;
    const int l16 = lane & 15, lq = lane >> 4;
    const int wm = wid >> 1, wn = wid & 1;

    // stage sources: A slots tid, 512+tid; B slot tid (granule inverse-swizzled)
    const int rA0 = tid >> 2, rA1 = 128 + (tid >> 2), g0 = tid & 3;
    const u16* pA0 = A  + (size_t)(m0 + rA0) * C_ + ((g0 ^ swz4(rA0)) * 8);
    const u16* pA1 = A  + (size_t)(m0 + rA1) * C_ + ((g0 ^ swz4(rA1)) * 8);
    const u16* pB0 = Bt + (size_t)(n0 + rA0) * C_ + ((g0 ^ swz4(rA0)) * 8);
    const int dA0 = tid * 8, dA1 = 4096 + tid * 8, dB = 8192 + tid * 8;   // u16, within sec

#define SLAB(T, CC)                                                                 \
    {                                                                               \
        const int bb = ((T) & 1) * 24576 + (CC) * 12288;                            \
        const int ko = (T) * 64 + (CC) * 32;                                        \
        gload_lds16(pA0 + ko, lds + bb + dA0);                                      \
        gload_lds16(pA1 + ko, lds + bb + dA1);                                      \
        gload_lds16(pB0 + ko, lds + bb + dB);                                       \
    }

    // fragment byte-offsets within one sec (A at 0, B at 16384)
    const char* lb = reinterpret_cast<const char*>(lds);
    int aoff[4], boff[4];
    #pragma unroll
    for (int i = 0; i < 4; ++i) {
        int ra = wm * 64 + i * 16 + l16;
        aoff[i] = ra * 64 + ((lq ^ swz4(ra)) * 16);
        int rb = wn * 64 + i * 16 + l16;
        boff[i] = 16384 + rb * 64 + ((lq ^ swz4(rb)) * 16);
    }

#define PHASE(T, CC)                                                                \
    {                                                                               \
        const char* sb = lb + (size_t)(((T) & 1) * 24576 + (CC) * 12288) * 2;       \
        bf16x8 af[4], bfv[4];                                                       \
        _Pragma("unroll")                                                           \
        for (int i = 0; i < 4; ++i) {                                               \
            af[i]  = *reinterpret_cast<const bf16x8*>(sb + aoff[i]);                \
            bfv[i] = *reinterpret_cast<const bf16x8*>(sb + boff[i]);                \
        }                                                                           \
        __builtin_amdgcn_s_setprio(1);                                              \
        _Pragma("unroll")                                                           \
        for (int mt = 0; mt < 4; ++mt)                                              \
            _Pragma("unroll")                                                       \
            for (int nt = 0; nt < 4; ++nt)                                          \
                acc[mt][nt] = __builtin_amdgcn_mfma_f32_16x16x32_bf16(               \
                    af[mt], bfv[nt], acc[mt][nt], 0, 0, 0);                         \
        __builtin_amdgcn_s_setprio(0);                                              \
    }

    SLAB(0, 0); SLAB(0, 1); SLAB(1, 0);     // prologue: 3 slabs ahead

    #pragma unroll
    for (int t = 0; t < 16; ++t) {
        // ---- phase A: compute slab (t,0) ----
        if (t < 15) { asm volatile("s_waitcnt vmcnt(6)" ::: "memory"); }
        else        { asm volatile("s_waitcnt vmcnt(3)" ::: "memory"); }
        __builtin_amdgcn_sched_barrier(0);
        __builtin_amdgcn_s_barrier();
        __builtin_amdgcn_sched_barrier(0);
        if (t + 1 < 16) SLAB(t + 1, 1);
        PHASE(t, 0);
        // ---- phase B: compute slab (t,1) ----
        if (t < 15) { asm volatile("s_waitcnt vmcnt(6)" ::: "memory"); }
        else        { asm volatile("s_waitcnt vmcnt(0)" ::: "memory"); }
        __builtin_amdgcn_sched_barrier(0);
        __builtin_amdgcn_s_barrier();
        __builtin_amdgcn_sched_barrier(0);
        if (t + 2 < 16) SLAB(t + 2, 0);
        PHASE(t, 1);
    }
#undef SLAB
#undef PHASE
}

// ---------------- QKV GEMM: q,k -> [B,H,T,D]; V written TRANSPOSED -> vT [B,H,D,T] ----------------
__global__ __launch_bounds__(512, 2) void qkv_gemm(const u16* __restrict__ xb, const u16* __restrict__ Wt,
                                                   u16* __restrict__ q, u16* __restrict__ k,
                                                   u16* __restrict__ vT) {
    __shared__ u16 lds[49152];     // 96 KiB
    f32x4 acc[4][4];
    #pragma unroll
    for (int i = 0; i < 4; ++i)
        #pragma unroll
        for (int j = 0; j < 4; ++j) { acc[i][j][0]=0.f; acc[i][j][1]=0.f; acc[i][j][2]=0.f; acc[i][j][3]=0.f; }
    const int m0 = blockIdx.x * 256, n0 = blockIdx.y * 128;
    gemm_slab(xb, Wt, m0, n0, lds, acc);

    const int tid = threadIdx.x, wid = tid >> 6, lane = tid & 63;
    const int l16 = lane & 15, lq = lane >> 4;
    const int wm = wid >> 1, wn = wid & 1;
    const int which = n0 >> 10;                         // block-uniform
    if (which < 2) {
        u16* dst0 = (which == 0 ? q : k);
        #pragma unroll
        for (int mt = 0; mt < 4; ++mt) {
            #pragma unroll
            for (int j = 0; j < 4; ++j) {
                int m = m0 + wm * 64 + mt * 16 + lq * 4 + j;
                int b = m >> 11, t = m & (T_ - 1);
                #pragma unroll
                for (int nt = 0; nt < 4; ++nt) {
                    int n = n0 + wn * 64 + nt * 16 + l16;
                    int h = (n >> 6) & 15, d = n & 63;
                    dst0[((size_t)(b * H_ + h) * T_ + t) * D_ + d] = f2bf(acc[mt][nt][j]);
                }
            }
        }
    } else {
        // V transposed: vT[(b*H+h)*D + d][t]; 4 consecutive t (j) -> 8B store
        #pragma unroll
        for (int mt = 0; mt < 4; ++mt) {
            int tb = m0 + wm * 64 + mt * 16 + lq * 4;
            int b = tb >> 11, t = tb & (T_ - 1);
            #pragma unroll
            for (int nt = 0; nt < 4; ++nt) {
                int n = n0 + wn * 64 + nt * 16 + l16;
                int h = (n >> 6) & 15, d = n & 63;
                ushort4v pk;
                pk[0] = f2bf(acc[mt][nt][0]); pk[1] = f2bf(acc[mt][nt][1]);
                pk[2] = f2bf(acc[mt][nt][2]); pk[3] = f2bf(acc[mt][nt][3]);
                *reinterpret_cast<ushort4v*>(vT + ((size_t)(b * H_ + h) * D_ + d) * T_ + t) = pk;
            }
        }
    }
}

// ---------------- Output GEMM: [8192x1024]@[1024x1024] + bias -> fp32 ----------------
__global__ __launch_bounds__(512, 2) void out_gemm(const u16* __restrict__ ob, const u16* __restrict__ Wpt,
                                                   const float* __restrict__ bp, float* __restrict__ out) {
    __shared__ u16 lds[49152];
    f32x4 acc[4][4];
    #pragma unroll
    for (int i = 0; i < 4; ++i)
        #pragma unroll
        for (int j = 0; j < 4; ++j) { acc[i][j][0]=0.f; acc[i][j][1]=0.f; acc[i][j][2]=0.f; acc[i][j][3]=0.f; }
    const int m0 = blockIdx.x * 256, n0 = blockIdx.y * 128;
    gemm_slab(ob, Wpt, m0, n0, lds, acc);

    const int tid = threadIdx.x, wid = tid >> 6, lane = tid & 63;
    const int l16 = lane & 15, lq = lane >> 4;
    const int wm = wid >> 1, wn = wid & 1;
    float bv[4];
    #pragma unroll
    for (int nt = 0; nt < 4; ++nt) bv[nt] = bp[n0 + wn * 64 + nt * 16 + l16];
    #pragma unroll
    for (int mt = 0; mt < 4; ++mt) {
        #pragma unroll
        for (int j = 0; j < 4; ++j) {
            int m = m0 + wm * 64 + mt * 16 + lq * 4 + j;
            #pragma unroll
            for (int nt = 0; nt < 4; ++nt) {
                int n = n0 + wn * 64 + nt * 16 + l16;
                out[(size_t)m * C_ + n] = acc[mt][nt][j] + bv[nt];
            }
        }
    }
}

// ---------------- attn compute tile (unchanged) ----------------
template<int CUR>
__device__ __forceinline__ void attn_tile(const char* const (&pf)[4], const bf16x8 (&qf)[4],
                                          const f32x16& z16, float& lrun,
                                          f32x16& oacc0, f32x16& oacc1,
                                          bool isdiag, int relq, int hi) {
    f32x16 st0, st1;
    __builtin_amdgcn_s_setprio(1);
    {
        bf16x8 ka0 = *reinterpret_cast<const bf16x8*>(pf[0] + CUR * 32768);
        bf16x8 ka1 = *reinterpret_cast<const bf16x8*>(pf[0] + CUR * 32768 + 4096);
        st0 = __builtin_amdgcn_mfma_f32_32x32x16_bf16(ka0, qf[0], z16, 0, 0, 0);
        st1 = __builtin_amdgcn_mfma_f32_32x32x16_bf16(ka1, qf[0], z16, 0, 0, 0);
    }
    #pragma unroll
    for (int kc = 1; kc < 4; ++kc) {
        bf16x8 ka0 = *reinterpret_cast<const bf16x8*>(pf[kc] + CUR * 32768);
        bf16x8 ka1 = *reinterpret_cast<const bf16x8*>(pf[kc] + CUR * 32768 + 4096);
        st0 = __builtin_amdgcn_mfma_f32_32x32x16_bf16(ka0, qf[kc], st0, 0, 0, 0);
        st1 = __builtin_amdgcn_mfma_f32_32x32x16_bf16(ka1, qf[kc], st1, 0, 0, 0);
    }
    __builtin_amdgcn_s_setprio(0);

    if (isdiag) {
        #pragma unroll
        for (int rr = 0; rr < 16; ++rr) {
            int sl = (rr & 3) + 8 * (rr >> 2) + 4 * hi;
            if (sl > relq)      st0[rr] = -INFINITY;
            if (sl + 32 > relq) st1[rr] = -INFINITY;
        }
    }

    float rsum = 0.f;
    #pragma unroll
    for (int rr = 0; rr < 16; ++rr) {
        st0[rr] = __builtin_amdgcn_exp2f(st0[rr]);
        st1[rr] = __builtin_amdgcn_exp2f(st1[rr]);
        rsum += st0[rr] + st1[rr];
    }
    rsum += __shfl_xor(rsum, 32);
    lrun += rsum;

    bf16x8 pa0, pa1, pa2, pa3;
#if __has_builtin(__builtin_amdgcn_permlane32_swap)
#define MK_PA(PA, SV, RB)                                                          \
    {                                                                              \
        int X0 = (int)pkt(SV[RB + 0], SV[RB + 1]);                                 \
        int X1 = (int)pkt(SV[RB + 2], SV[RB + 3]);                                 \
        int Y0 = (int)pkt(SV[RB + 4], SV[RB + 5]);                                 \
        int Y1 = (int)pkt(SV[RB + 6], SV[RB + 7]);                                 \
        int2v r0 = __builtin_amdgcn_permlane32_swap(X0, Y0, false, false);         \
        int2v r1 = __builtin_amdgcn_permlane32_swap(X1, Y1, false, false);         \
        uint4v w; w[0] = (unsigned)r0[0]; w[1] = (unsigned)r1[0];                  \
        w[2] = (unsigned)r0[1]; w[3] = (unsigned)r1[1];                            \
        PA = __builtin_bit_cast(bf16x8, w);                                        \
    }
#else
#define MK_PA(PA, SV, RB)                                                          \
    {                                                                              \
        unsigned X0 = pkt(SV[RB + 0], SV[RB + 1]);                                 \
        unsigned X1 = pkt(SV[RB + 2], SV[RB + 3]);                                 \
        unsigned Y0 = pkt(SV[RB + 4], SV[RB + 5]);                                 \
        unsigned sX0 = __shfl_xor(X0, 32), sY0 = __shfl_xor(Y0, 32);               \
        unsigned Y1 = pkt(SV[RB + 6], SV[RB + 7]);                                 \
        unsigned sX1 = __shfl_xor(X1, 32), sY1 = __shfl_xor(Y1, 32);               \
        uint4v w;                                                                  \
        w[0] = hi ? sY0 : X0; w[1] = hi ? sY1 : X1;                                \
        w[2] = hi ? Y0 : sX0; w[3] = hi ? Y1 : sX1;                                \
        PA = __builtin_bit_cast(bf16x8, w);                                        \
    }
#endif
    MK_PA(pa0, st0, 0); MK_PA(pa1, st0, 8); MK_PA(pa2, st1, 0); MK_PA(pa3, st1, 8);
#undef MK_PA

    __builtin_amdgcn_s_setprio(1);
#define PV_STEP(SCJ, PAV)                                                          \
    {                                                                              \
        bf16x8 va0 = *reinterpret_cast<const bf16x8*>(pf[SCJ] + CUR * 32768 + 16384);        \
        bf16x8 va1 = *reinterpret_cast<const bf16x8*>(pf[SCJ] + CUR * 32768 + 16384 + 4096); \
        oacc0 = __builtin_amdgcn_mfma_f32_32x32x16_bf16(va0, PAV, oacc0, 0, 0, 0); \
        oacc1 = __builtin_amdgcn_mfma_f32_32x32x16_bf16(va1, PAV, oacc1, 0, 0, 0); \
    }
    PV_STEP(0, pa0) PV_STEP(1, pa1) PV_STEP(2, pa2) PV_STEP(3, pa3)
#undef PV_STEP
    __builtin_amdgcn_s_setprio(0);
}

// ---------------- MFMA flash attention (unchanged, XCD-locality decode) ----------------
__global__ __launch_bounds__(512, 4) void attn_mfma(const u16* __restrict__ q,
                                                    const u16* __restrict__ k,
                                                    const u16* __restrict__ vT,
                                                    u16* __restrict__ o) {
    __shared__ u16 smem[32768];

    const int tid  = threadIdx.x;
    const int wid  = tid >> 6;
    const int lane = tid & 63;
    const int l31  = lane & 31;
    const int hi   = lane >> 5;

    const int lin = blockIdx.x;       // 0..511
    const int xcd = lin & 7;
    const int i   = (lin >> 3) & 31;
    const int f   = lin >> 8;
    const int bh  = xcd * 8 + (i & 7);
    const int e   = i >> 3;
    const int qb  = f ? (7 - e) : e;

    const int q0 = qb * 256;
    const size_t base = (size_t)bh * T_ * D_;
    const u16* kp  = k  + base;
    const u16* vtp = vT + (size_t)bh * D_ * T_;
    const int qglob = q0 + wid * 32 + l31;

    bf16x8 qf[4];
    {
        const u16* qp = q + base + (size_t)qglob * D_;
        #pragma unroll
        for (int kc = 0; kc < 4; ++kc)
            qf[kc] = *reinterpret_cast<const bf16x8*>(qp + kc * 16 + hi * 8);
    }

    const int rw = tid >> 3;
    const int cg = (tid & 7) ^ (rw & 7);
    const u16* gK = kp  + (size_t)rw * D_ + cg * 8;
    const u16* gV = vtp + (size_t)rw * T_ + cg * 8;

    u16* sbase = &smem[0];
    u16* dK = sbase + tid * 8;
    u16* dV = sbase + 8192 + tid * 8;

    const char* pf[4];
    #pragma unroll
    for (int j = 0; j < 4; ++j)
        pf[j] = reinterpret_cast<const char*>(sbase) + l31 * 128 + (((j * 2 + hi) ^ (l31 & 7)) << 4);

    float lrun = 0.f;
    f32x16 oacc0, oacc1, z16;
    #pragma unroll
    for (int rr = 0; rr < 16; ++rr) { oacc0[rr] = 0.f; oacc1[rr] = 0.f; z16[rr] = 0.f; }

    const int ntile  = 4 * qb + 4;
    const int diag_t = 4 * qb + (wid >> 1);
    const int relq   = 32 * (wid & 1) + l31;

#define STG(BUFU16)                                                                \
    {                                                                              \
        gload_lds16(gK, dK + (BUFU16)); gload_lds16(gV, dV + (BUFU16));            \
        gK += 64 * D_; gV += 64;                                                   \
    }

    STG(0);
    __syncthreads();

    for (int tt = 0; tt < ntile; tt += 2) {
        if (tt + 1 < ntile) STG(16384);
        if (tt <= diag_t)
            attn_tile<0>(pf, qf, z16, lrun, oacc0, oacc1, tt == diag_t, relq, hi);
        __syncthreads();
        if (tt + 2 < ntile) STG(0);
        if (tt + 1 <= diag_t)
            attn_tile<1>(pf, qf, z16, lrun, oacc0, oacc1, tt + 1 == diag_t, relq, hi);
        __syncthreads();
    }
#undef STG

    float linv = 1.f / lrun;
    float* ot = reinterpret_cast<float*>(sbase) + wid * 2048;
    #pragma unroll
    for (int rr = 0; rr < 16; ++rr) {
        int d0v = (rr & 3) + 8 * (rr >> 2) + 4 * hi;
        int d1v = d0v + 32;
        ot[l31 * 64 + (((d0v >> 2) ^ (l31 & 7)) << 2) + (d0v & 3)] = oacc0[rr] * linv;
        ot[l31 * 64 + (((d1v >> 2) ^ (l31 & 7)) << 2) + (d1v & 3)] = oacc1[rr] * linv;
    }

    const int b = bh >> 4, h = bh & 15;
    const int qrow = lane >> 1;
    const int d0 = (lane & 1) * 32;
    u16 tmp[32];
    #pragma unroll
    for (int i2 = 0; i2 < 8; ++i2) {
        int g = ((d0 >> 2) + i2) ^ (qrow & 7);
        float4 fv = *reinterpret_cast<const float4*>(&ot[qrow * 64 + (g << 2)]);
        tmp[i2 * 4 + 0] = f2bf(fv.x); tmp[i2 * 4 + 1] = f2bf(fv.y);
        tmp[i2 * 4 + 2] = f2bf(fv.z); tmp[i2 * 4 + 3] = f2bf(fv.w);
    }
    u16* orow = o + ((size_t)b * T_ + q0 + wid * 32 + qrow) * C_ + h * 64 + d0;
    #pragma unroll
    for (int j = 0; j < 4; ++j)
        *reinterpret_cast<ushort8*>(orow + j * 8) = *reinterpret_cast<ushort8*>(&tmp[j * 8]);
}

extern "C" void kernel_launch(void* const* d_in, const int* in_sizes, int n_in,
                              void* d_out, int out_size, void* d_ws, size_t ws_size,
                              hipStream_t stream) {
    const float* x  = (const float*)d_in[0];
    const float* Wq = (const float*)d_in[1];
    const float* Wk = (const float*)d_in[2];
    const float* Wv = (const float*)d_in[3];
    const float* Wp = (const float*)d_in[4];
    const float* bp = (const float*)d_in[5];
    float* out = (float*)d_out;

    const size_t E = (size_t)M_ * C_;
    u16* xb  = (u16*)d_ws;
    u16* qb  = xb  + E;
    u16* kb  = qb  + E;
    u16* vTb = kb  + E;                      // V stored transposed [B,H,D,T] by qkv_gemm
    u16* obf = vTb + E;
    u16* Wt  = obf + E;                      // [3072][1024]
    u16* Wpt = Wt  + (size_t)3072 * 1024;    // [1024][1024]

    prep<<<dim3(5120), 256, 0, stream>>>(x, Wq, Wk, Wv, Wp, xb, Wt, Wpt);

    qkv_gemm<<<dim3(M_ / 256, 3072 / 128), 512, 0, stream>>>(xb, Wt, qb, kb, vTb);

    attn_mfma<<<dim3(512), 512, 0, stream>>>(qb, kb, vTb, obf);

    out_gemm<<<dim3(M_ / 256, C_ / 128), 512, 0, stream>>>(obf, Wpt, bp, out);
}